// Round 11
// baseline (2683.182 us; speedup 1.0000x reference)
//
#include <hip/hip_runtime.h>
#include <math.h>

#define N_LOCS 16384
#define START 4096
#define NB 12288
#define NMAT 96
#define KDIM 60

typedef __attribute__((ext_vector_type(8))) short short8;
typedef __attribute__((ext_vector_type(4))) float f32x4;

__global__ void minnz_kernel(const float* __restrict__ scales, unsigned* __restrict__ ws) {
    int idx = blockIdx.x * 256 + threadIdx.x;
    if (idx < NB) {
        float v = scales[START + idx];
        if (v != 0.0f) atomicMin(ws, __float_as_uint(v));
    }
}

__device__ __forceinline__ unsigned short f32_to_bf16_rne(float f, float* back) {
    unsigned u = __float_as_uint(f);
    unsigned r = (u + 0x7fffu + ((u >> 16) & 1u)) >> 16;
    *back = __uint_as_float(r << 16);
    return (unsigned short)r;
}

// ============ kernel 1: gram + transform + write g (r8-verified, unchanged) ============
__launch_bounds__(256)
__global__ void gram_kernel(const float* __restrict__ kp,
                            const float* __restrict__ aug,
                            const float* __restrict__ scales,
                            const float* __restrict__ nug,
                            const unsigned* __restrict__ ws,
                            float* __restrict__ out)
{
    const int b = blockIdx.x;
    const int t = threadIdx.x;
    const int ti = t >> 4, tj = t & 15;

    float* outG = out;                                   // [NB][96][96]
    float* outN = out + 2 * (size_t)NB * NMAT * NMAT;    // [NB]

    if (t == 0) outN[b] = nug[b];

    const size_t gbase = (size_t)b * (NMAT * NMAT);

    if (b == 0) {
        #pragma unroll
        for (int u = 0; u < 6; ++u) {
            int i = ti * 6 + u;
            #pragma unroll
            for (int v = 0; v < 6; ++v) {
                int j = tj * 6 + v;
                outG[gbase + (size_t)i * NMAT + j] = (i == j) ? 1.0f : 0.0f;
            }
        }
        return;
    }

    __shared__ char smem[37632];
    unsigned short* sxh  = (unsigned short*)smem;
    unsigned short* sxl  = (unsigned short*)(smem + 13824);
    float*          slin = (float*)smem;

    const float kp1 = kp[1], kp3 = kp[3], kp5 = kp[5], kp7 = kp[7];
    const float kp8 = kp[8], kp9 = kp[9], kp11 = kp[11];
    float sc = scales[START + b];
    if (sc == 0.0f) sc = __uint_as_float(ws[0]) * 0.5f;
    const float sigma   = __expf(kp1 + kp3 * __logf(sc));
    const float sigma2  = sigma * sigma;
    const float inv_ls2 = 1.0f / (3.0f * __expf(2.0f * kp11));
    const float inv_nug = 1.0f / nug[b];

    const int c = t & 63;
    float myscale = 0.0f;
    if (c < KDIM) {
        float kf = (c < 30) ? (float)(c + 1) : (float)(c - 29);
        float th = (c < 30) ? kp5 : kp8;
        float de = (c < 30) ? kp7 : kp9;
        myscale = __expf(th - 0.5f * __expf(de) * kf);
    }

    {
        const int rgrp = t >> 6;
        const size_t rowstride = (size_t)N_LOCS * 61;
        const size_t base = (size_t)(START + b) * 61 + 1 + c;
        for (int it = 0; it < 24; ++it) {
            int i = it * 4 + rgrp;
            float v = 0.0f;
            if (c < KDIM) {
                v = aug[base + (size_t)i * rowstride];
                v = (v != v) ? 0.0f : v;
                v *= myscale;
            }
            float fh;
            unsigned short hb = f32_to_bf16_rne(v, &fh);
            float dummy;
            unsigned short lb = f32_to_bf16_rne(v - fh, &dummy);
            sxh[i * 72 + c] = hb;
            sxl[i * 72 + c] = lb;
        }
    }
    __syncthreads();

    {
        const int w  = t >> 6;
        const int l  = t & 63;
        const int wrB = (w >> 1) * 48;
        const int wcB = (w & 1) * 48;
        const int lrow = l & 15;
        const int lk   = (l >> 4) * 8;

        f32x4 gacc[3][3];
        #pragma unroll
        for (int a = 0; a < 3; ++a)
            #pragma unroll
            for (int cc = 0; cc < 3; ++cc) gacc[a][cc] = (f32x4){0.f, 0.f, 0.f, 0.f};

        #pragma unroll
        for (int k0 = 0; k0 < 64; k0 += 32) {
            #pragma unroll
            for (int a = 0; a < 3; ++a) {
                int arow = wrB + a * 16 + lrow;
                short8 Ah = *(const short8*)&sxh[arow * 72 + k0 + lk];
                short8 Al = *(const short8*)&sxl[arow * 72 + k0 + lk];
                #pragma unroll
                for (int cc = 0; cc < 3; ++cc) {
                    int brow = wcB + cc * 16 + lrow;
                    short8 Bh = *(const short8*)&sxh[brow * 72 + k0 + lk];
                    short8 Bl = *(const short8*)&sxl[brow * 72 + k0 + lk];
                    gacc[a][cc] = __builtin_amdgcn_mfma_f32_16x16x32_bf16(Ah, Bh, gacc[a][cc], 0, 0, 0);
                    gacc[a][cc] = __builtin_amdgcn_mfma_f32_16x16x32_bf16(Ah, Bl, gacc[a][cc], 0, 0, 0);
                    gacc[a][cc] = __builtin_amdgcn_mfma_f32_16x16x32_bf16(Al, Bh, gacc[a][cc], 0, 0, 0);
                    gacc[a][cc] = __builtin_amdgcn_mfma_f32_16x16x32_bf16(Al, Bl, gacc[a][cc], 0, 0, 0);
                }
            }
        }
        __syncthreads();

        #pragma unroll
        for (int a = 0; a < 3; ++a)
            #pragma unroll
            for (int cc = 0; cc < 3; ++cc) {
                int col = wcB + cc * 16 + lrow;
                #pragma unroll
                for (int r = 0; r < 4; ++r) {
                    int row = wrB + a * 16 + (l >> 4) * 4 + r;
                    slin[row * 98 + col] = gacc[a][cc][r];
                }
            }
    }
    __syncthreads();

    float acc[6][6];
    #pragma unroll
    for (int u = 0; u < 6; ++u) {
        int rb = (ti * 6 + u) * 98;
        #pragma unroll
        for (int v = 0; v < 6; v += 2) {
            float2 p = *(const float2*)&slin[rb + tj * 6 + v];
            acc[u][v] = p.x; acc[u][v + 1] = p.y;
        }
    }
    float di[6], dj[6];
    #pragma unroll
    for (int u = 0; u < 6; ++u) { int i = ti * 6 + u; di[u] = slin[i * 98 + i]; }
    #pragma unroll
    for (int v = 0; v < 6; ++v) { int j = tj * 6 + v; dj[v] = slin[j * 98 + j]; }

    #pragma unroll
    for (int u = 0; u < 6; ++u) {
        int i = ti * 6 + u;
        #pragma unroll
        for (int v = 0; v < 6; ++v) {
            int j = tj * 6 + v;
            float lin = acc[u][v];
            float d2 = (di[u] + dj[v] - 2.0f * lin) * inv_ls2;
            d2 = fmaxf(d2, 0.0f);
            float cc = sqrtf(3.0f * d2);
            float nl = (1.0f + cc) * __expf(-cc);
            acc[u][v] = fmaf(sigma2, nl, lin) * inv_nug + ((i == j) ? 1.0f : 0.0f);
        }
    }
    #pragma unroll
    for (int u = 0; u < 6; ++u) {
        size_t row = gbase + (size_t)(ti * 6 + u) * NMAT + tj * 6;
        #pragma unroll
        for (int v = 0; v < 6; v += 2) {
            *(float2*)&outG[row + v] = make_float2(acc[u][v], acc[u][v + 1]);
        }
    }
}

// ============ kernel 2: WAVE-PER-MATRIX cholesky (r5 phase bodies, no barriers) ============
// Lane (wi,wj) of each wave owns tiles T00=(wi,wj), T10=(8+wi,wj), T11=(8+wi,8+wj).
// Upper-right quadrant tiles are never read by chol; written as zeros.
// Phase bodies are VERBATIM r5; slot selection is compile-time (jb loop unrolled).
// No __syncthreads: A->B->C ordering is wave program order (in-order DS pipe +
// compiler lgkmcnt waits on LDS aliasing).

#define PHASE_A(D) do {                                                          \
    _Pragma("unroll") for (int c2 = 0; c2 < 6; ++c2) {                           \
        float s = D[c2][c2];                                                     \
        _Pragma("unroll") for (int m = 0; m < 6; ++m) if (m < c2) s -= D[c2][m] * D[c2][m]; \
        float l = sqrtf(s);                                                      \
        D[c2][c2] = l;                                                           \
        float rinv = 1.0f / l;                                                   \
        rinvp[c2] = rinv;                                                        \
        _Pragma("unroll") for (int rr = 0; rr < 6; ++rr) if (rr > c2) {          \
            float s2 = D[rr][c2];                                                \
            _Pragma("unroll") for (int m = 0; m < 6; ++m) if (m < c2) s2 -= D[rr][m] * D[c2][m]; \
            D[rr][c2] = s2 * rinv;                                               \
        }                                                                        \
    }                                                                            \
    _Pragma("unroll") for (int u = 0; u < 6; ++u) {                              \
        *(float4*)&L6p[u * 8]     = make_float4(D[u][0], D[u][1], D[u][2], D[u][3]); \
        *(float2*)&L6p[u * 8 + 4] = make_float2(D[u][4], D[u][5]);               \
    }                                                                            \
} while (0)

#define PHASE_B(D, TIEFF) do {                                                   \
    float A6[6][6], rinv6[6];                                                    \
    _Pragma("unroll") for (int u = 0; u < 6; ++u) {                              \
        float4 p = *(const float4*)&L6p[u * 8];                                  \
        float2 q = *(const float2*)&L6p[u * 8 + 4];                              \
        A6[u][0] = p.x; A6[u][1] = p.y; A6[u][2] = p.z; A6[u][3] = p.w;          \
        A6[u][4] = q.x; A6[u][5] = q.y;                                          \
    }                                                                            \
    _Pragma("unroll") for (int c2 = 0; c2 < 6; ++c2) rinv6[c2] = rinvp[c2];      \
    _Pragma("unroll") for (int u = 0; u < 6; ++u) {                              \
        _Pragma("unroll") for (int c2 = 0; c2 < 6; ++c2) {                       \
            float s = D[u][c2];                                                  \
            _Pragma("unroll") for (int m = 0; m < 6; ++m) if (m < c2) s -= D[u][m] * A6[c2][m]; \
            D[u][c2] = s * rinv6[c2];                                            \
        }                                                                        \
        int prow = (TIEFF) * 6 + u;                                              \
        *(float4*)&panel[prow * 12]     = make_float4(D[u][0], D[u][1], D[u][2], D[u][3]); \
        *(float2*)&panel[prow * 12 + 4] = make_float2(D[u][4], D[u][5]);         \
    }                                                                            \
} while (0)

#define PHASE_C(D, TIEFF, TJEFF) do {                                            \
    float pv[6][6];                                                              \
    _Pragma("unroll") for (int v = 0; v < 6; ++v) {                              \
        int prow = (TJEFF) * 6 + v;                                              \
        float4 p = *(const float4*)&panel[prow * 12];                            \
        float2 q = *(const float2*)&panel[prow * 12 + 4];                        \
        pv[v][0] = p.x; pv[v][1] = p.y; pv[v][2] = p.z; pv[v][3] = p.w;          \
        pv[v][4] = q.x; pv[v][5] = q.y;                                          \
    }                                                                            \
    _Pragma("unroll") for (int u = 0; u < 6; ++u) {                              \
        int prow = (TIEFF) * 6 + u;                                              \
        float4 p = *(const float4*)&panel[prow * 12];                            \
        float2 q = *(const float2*)&panel[prow * 12 + 4];                        \
        float pu0 = p.x, pu1 = p.y, pu2 = p.z, pu3 = p.w, pu4 = q.x, pu5 = q.y;  \
        _Pragma("unroll") for (int v = 0; v < 6; ++v) {                          \
            float s = D[u][v];                                                   \
            s = fmaf(-pu0, pv[v][0], s);                                         \
            s = fmaf(-pu1, pv[v][1], s);                                         \
            s = fmaf(-pu2, pv[v][2], s);                                         \
            s = fmaf(-pu3, pv[v][3], s);                                         \
            s = fmaf(-pu4, pv[v][4], s);                                         \
            s = fmaf(-pu5, pv[v][5], s);                                         \
            D[u][v] = s;                                                         \
        }                                                                        \
    }                                                                            \
} while (0)

#define STORE_TILE(D, TIEFF, TJEFF) do {                                         \
    _Pragma("unroll") for (int u = 0; u < 6; ++u) {                              \
        const int i2 = (TIEFF) * 6 + u;                                          \
        size_t rowp = gbase + (size_t)i2 * NMAT + (TJEFF) * 6;                   \
        _Pragma("unroll") for (int v = 0; v < 6; v += 2) {                       \
            int j0 = (TJEFF) * 6 + v;                                            \
            float a0 = D[u][v], a1 = D[u][v + 1];                                \
            if ((TIEFF) < (TJEFF)) { a0 = 0.0f; a1 = 0.0f; }                     \
            else if ((TIEFF) == (TJEFF)) {                                       \
                if (j0 > i2)     a0 = 0.0f;                                      \
                if (j0 + 1 > i2) a1 = 0.0f;                                      \
            }                                                                    \
            *(float2*)&outL[rowp + v] = make_float2(a0, a1);                     \
        }                                                                        \
    }                                                                            \
} while (0)

#define LOAD_TILE(D, TIEFF, TJEFF) do {                                          \
    _Pragma("unroll") for (int u = 0; u < 6; ++u) {                              \
        size_t rowp = gbase + (size_t)((TIEFF) * 6 + u) * NMAT + (TJEFF) * 6;    \
        float2 p0 = *(const float2*)&outG[rowp + 0];                             \
        float2 p1 = *(const float2*)&outG[rowp + 2];                             \
        float2 p2 = *(const float2*)&outG[rowp + 4];                             \
        D[u][0] = p0.x; D[u][1] = p0.y; D[u][2] = p1.x;                          \
        D[u][3] = p1.y; D[u][4] = p2.x; D[u][5] = p2.y;                          \
    }                                                                            \
} while (0)

__launch_bounds__(256)
__global__ void chol_kernel(const float* __restrict__ outG,
                            float* __restrict__ outL)
{
    const int w    = threadIdx.x >> 6;   // wave id 0..3 -> matrix
    const int lane = threadIdx.x & 63;
    const int wi   = lane >> 3;          // 0..7 row-tile
    const int wj   = lane & 7;           // 0..7 col-tile
    const int b    = blockIdx.x * 4 + w;
    const size_t gbase = (size_t)b * (NMAT * NMAT);

    __shared__ float spanel_all[4][96][12];
    __shared__ float sL6_all[4][6][8];
    __shared__ float srinv_all[4][8];
    float* panel = &spanel_all[w][0][0];
    float* L6p   = &sL6_all[w][0][0];
    float* rinvp = &srinv_all[w][0];

    float acc00[6][6], acc10[6][6], acc11[6][6];

    LOAD_TILE(acc00, wi,     wj);
    LOAD_TILE(acc10, 8 + wi, wj);
    LOAD_TILE(acc11, 8 + wi, 8 + wj);

    #pragma unroll
    for (int jb = 0; jb < 16; ++jb) {
        const int J = jb & 7;
        if (jb < 8) {
            // Phase A: owner tile (jb,jb) = T00 of lane (J,J)
            if (wi == J && wj == J) PHASE_A(acc00);
            // Phase B: column jb
            if (wj == J && wi > J) PHASE_B(acc00, wi);
            if (wj == J)           PHASE_B(acc10, 8 + wi);   // ti=8+wi > jb always
            // Phase C: trailing update
            if (wj > J && wi >= wj) PHASE_C(acc00, wi, wj);
            if (wj > J)             PHASE_C(acc10, 8 + wi, wj);       // ti>=tj always
            if (wi >= wj)           PHASE_C(acc11, 8 + wi, 8 + wj);   // tj>jb always
        } else {
            // Phase A: owner tile (jb,jb) = T11 of lane (J,J)
            if (wi == J && wj == J) PHASE_A(acc11);
            // Phase B
            if (wj == J && wi > J) PHASE_B(acc11, 8 + wi);
            // Phase C
            if (wj > J && wi >= wj) PHASE_C(acc11, 8 + wi, 8 + wj);
        }
    }

    // ---- write L: three computed quadrant slots + zero upper-right quadrant ----
    STORE_TILE(acc00, wi,     wj);
    STORE_TILE(acc10, 8 + wi, wj);
    STORE_TILE(acc11, 8 + wi, 8 + wj);
    #pragma unroll
    for (int u = 0; u < 6; ++u) {
        size_t rowp = gbase + (size_t)(wi * 6 + u) * NMAT + (8 + wj) * 6;
        *(float2*)&outL[rowp + 0] = make_float2(0.0f, 0.0f);
        *(float2*)&outL[rowp + 2] = make_float2(0.0f, 0.0f);
        *(float2*)&outL[rowp + 4] = make_float2(0.0f, 0.0f);
    }
}

extern "C" void kernel_launch(void* const* d_in, const int* in_sizes, int n_in,
                              void* d_out, int out_size, void* d_ws, size_t ws_size,
                              hipStream_t stream) {
    const float* kp     = (const float*)d_in[0];
    const float* aug    = (const float*)d_in[1];
    const float* scales = (const float*)d_in[2];
    const float* nug    = (const float*)d_in[3];
    float* out = (float*)d_out;
    unsigned* ws = (unsigned*)d_ws;

    float* outG = out;
    float* outL = out + (size_t)NB * NMAT * NMAT;

    hipMemsetAsync(ws, 0xFF, 4, stream);
    minnz_kernel<<<(NB + 255) / 256, 256, 0, stream>>>(scales, ws);
    gram_kernel<<<NB, 256, 0, stream>>>(kp, aug, scales, nug, ws, out);
    chol_kernel<<<NB / 4, 256, 0, stream>>>(outG, outL);
}

// Round 12
// 1217.091 us; speedup vs baseline: 2.2046x; 2.2046x over previous
//
#include <hip/hip_runtime.h>
#include <math.h>

#define N_LOCS 16384
#define START 4096
#define NB 12288
#define NMAT 96
#define KDIM 60

typedef __attribute__((ext_vector_type(8))) short short8;
typedef __attribute__((ext_vector_type(4))) float f32x4;

__global__ void minnz_kernel(const float* __restrict__ scales, unsigned* __restrict__ ws) {
    int idx = blockIdx.x * 256 + threadIdx.x;
    if (idx < NB) {
        float v = scales[START + idx];
        if (v != 0.0f) atomicMin(ws, __float_as_uint(v));
    }
}

__device__ __forceinline__ unsigned short f32_to_bf16_rne(float f, float* back) {
    unsigned u = __float_as_uint(f);
    unsigned r = (u + 0x7fffu + ((u >> 16) & 1u)) >> 16;
    *back = __uint_as_float(r << 16);
    return (unsigned short)r;
}

// ============ kernel 1: gram + transform + write g (r8-verified, unchanged) ============
__launch_bounds__(256)
__global__ void gram_kernel(const float* __restrict__ kp,
                            const float* __restrict__ aug,
                            const float* __restrict__ scales,
                            const float* __restrict__ nug,
                            const unsigned* __restrict__ ws,
                            float* __restrict__ out)
{
    const int b = blockIdx.x;
    const int t = threadIdx.x;
    const int ti = t >> 4, tj = t & 15;

    float* outG = out;                                   // [NB][96][96]
    float* outN = out + 2 * (size_t)NB * NMAT * NMAT;    // [NB]

    if (t == 0) outN[b] = nug[b];

    const size_t gbase = (size_t)b * (NMAT * NMAT);

    if (b == 0) {
        #pragma unroll
        for (int u = 0; u < 6; ++u) {
            int i = ti * 6 + u;
            #pragma unroll
            for (int v = 0; v < 6; ++v) {
                int j = tj * 6 + v;
                outG[gbase + (size_t)i * NMAT + j] = (i == j) ? 1.0f : 0.0f;
            }
        }
        return;
    }

    __shared__ char smem[37632];
    unsigned short* sxh  = (unsigned short*)smem;
    unsigned short* sxl  = (unsigned short*)(smem + 13824);
    float*          slin = (float*)smem;

    const float kp1 = kp[1], kp3 = kp[3], kp5 = kp[5], kp7 = kp[7];
    const float kp8 = kp[8], kp9 = kp[9], kp11 = kp[11];
    float sc = scales[START + b];
    if (sc == 0.0f) sc = __uint_as_float(ws[0]) * 0.5f;
    const float sigma   = __expf(kp1 + kp3 * __logf(sc));
    const float sigma2  = sigma * sigma;
    const float inv_ls2 = 1.0f / (3.0f * __expf(2.0f * kp11));
    const float inv_nug = 1.0f / nug[b];

    const int c = t & 63;
    float myscale = 0.0f;
    if (c < KDIM) {
        float kf = (c < 30) ? (float)(c + 1) : (float)(c - 29);
        float th = (c < 30) ? kp5 : kp8;
        float de = (c < 30) ? kp7 : kp9;
        myscale = __expf(th - 0.5f * __expf(de) * kf);
    }

    {
        const int rgrp = t >> 6;
        const size_t rowstride = (size_t)N_LOCS * 61;
        const size_t base = (size_t)(START + b) * 61 + 1 + c;
        for (int it = 0; it < 24; ++it) {
            int i = it * 4 + rgrp;
            float v = 0.0f;
            if (c < KDIM) {
                v = aug[base + (size_t)i * rowstride];
                v = (v != v) ? 0.0f : v;
                v *= myscale;
            }
            float fh;
            unsigned short hb = f32_to_bf16_rne(v, &fh);
            float dummy;
            unsigned short lb = f32_to_bf16_rne(v - fh, &dummy);
            sxh[i * 72 + c] = hb;
            sxl[i * 72 + c] = lb;
        }
    }
    __syncthreads();

    {
        const int w  = t >> 6;
        const int l  = t & 63;
        const int wrB = (w >> 1) * 48;
        const int wcB = (w & 1) * 48;
        const int lrow = l & 15;
        const int lk   = (l >> 4) * 8;

        f32x4 gacc[3][3];
        #pragma unroll
        for (int a = 0; a < 3; ++a)
            #pragma unroll
            for (int cc = 0; cc < 3; ++cc) gacc[a][cc] = (f32x4){0.f, 0.f, 0.f, 0.f};

        #pragma unroll
        for (int k0 = 0; k0 < 64; k0 += 32) {
            #pragma unroll
            for (int a = 0; a < 3; ++a) {
                int arow = wrB + a * 16 + lrow;
                short8 Ah = *(const short8*)&sxh[arow * 72 + k0 + lk];
                short8 Al = *(const short8*)&sxl[arow * 72 + k0 + lk];
                #pragma unroll
                for (int cc = 0; cc < 3; ++cc) {
                    int brow = wcB + cc * 16 + lrow;
                    short8 Bh = *(const short8*)&sxh[brow * 72 + k0 + lk];
                    short8 Bl = *(const short8*)&sxl[brow * 72 + k0 + lk];
                    gacc[a][cc] = __builtin_amdgcn_mfma_f32_16x16x32_bf16(Ah, Bh, gacc[a][cc], 0, 0, 0);
                    gacc[a][cc] = __builtin_amdgcn_mfma_f32_16x16x32_bf16(Ah, Bl, gacc[a][cc], 0, 0, 0);
                    gacc[a][cc] = __builtin_amdgcn_mfma_f32_16x16x32_bf16(Al, Bh, gacc[a][cc], 0, 0, 0);
                    gacc[a][cc] = __builtin_amdgcn_mfma_f32_16x16x32_bf16(Al, Bl, gacc[a][cc], 0, 0, 0);
                }
            }
        }
        __syncthreads();

        #pragma unroll
        for (int a = 0; a < 3; ++a)
            #pragma unroll
            for (int cc = 0; cc < 3; ++cc) {
                int col = wcB + cc * 16 + lrow;
                #pragma unroll
                for (int r = 0; r < 4; ++r) {
                    int row = wrB + a * 16 + (l >> 4) * 4 + r;
                    slin[row * 98 + col] = gacc[a][cc][r];
                }
            }
    }
    __syncthreads();

    float acc[6][6];
    #pragma unroll
    for (int u = 0; u < 6; ++u) {
        int rb = (ti * 6 + u) * 98;
        #pragma unroll
        for (int v = 0; v < 6; v += 2) {
            float2 p = *(const float2*)&slin[rb + tj * 6 + v];
            acc[u][v] = p.x; acc[u][v + 1] = p.y;
        }
    }
    float di[6], dj[6];
    #pragma unroll
    for (int u = 0; u < 6; ++u) { int i = ti * 6 + u; di[u] = slin[i * 98 + i]; }
    #pragma unroll
    for (int v = 0; v < 6; ++v) { int j = tj * 6 + v; dj[v] = slin[j * 98 + j]; }

    #pragma unroll
    for (int u = 0; u < 6; ++u) {
        int i = ti * 6 + u;
        #pragma unroll
        for (int v = 0; v < 6; ++v) {
            int j = tj * 6 + v;
            float lin = acc[u][v];
            float d2 = (di[u] + dj[v] - 2.0f * lin) * inv_ls2;
            d2 = fmaxf(d2, 0.0f);
            float cc = sqrtf(3.0f * d2);
            float nl = (1.0f + cc) * __expf(-cc);
            acc[u][v] = fmaf(sigma2, nl, lin) * inv_nug + ((i == j) ? 1.0f : 0.0f);
        }
    }
    #pragma unroll
    for (int u = 0; u < 6; ++u) {
        size_t row = gbase + (size_t)(ti * 6 + u) * NMAT + tj * 6;
        #pragma unroll
        for (int v = 0; v < 6; v += 2) {
            *(float2*)&outG[row + v] = make_float2(acc[u][v], acc[u][v + 1]);
        }
    }
}

// ====== kernel 2: cholesky, r9-verified phase code, TWO matrices per block ======
// Same ti/tj map, same barrier structure, same phase bodies (verbatim r5/r9);
// each phase body simply runs twice (matrix A then matrix B, separate LDS).
// Halves barrier count per matrix; the two owner A-chains overlap via ILP.

#define CHOL_A(D, L6P, RINVP) do {                                               \
    _Pragma("unroll") for (int c2 = 0; c2 < 6; ++c2) {                           \
        float s = D[c2][c2];                                                     \
        _Pragma("unroll") for (int m = 0; m < 6; ++m) if (m < c2) s -= D[c2][m] * D[c2][m]; \
        float l = sqrtf(s);                                                      \
        D[c2][c2] = l;                                                           \
        float rinv = 1.0f / l;                                                   \
        RINVP[c2] = rinv;                                                        \
        _Pragma("unroll") for (int rr = 0; rr < 6; ++rr) if (rr > c2) {          \
            float s2 = D[rr][c2];                                                \
            _Pragma("unroll") for (int m = 0; m < 6; ++m) if (m < c2) s2 -= D[rr][m] * D[c2][m]; \
            D[rr][c2] = s2 * rinv;                                               \
        }                                                                        \
    }                                                                            \
    _Pragma("unroll") for (int u = 0; u < 6; ++u) {                              \
        *(float4*)&L6P[u * 8]     = make_float4(D[u][0], D[u][1], D[u][2], D[u][3]); \
        *(float2*)&L6P[u * 8 + 4] = make_float2(D[u][4], D[u][5]);               \
    }                                                                            \
} while (0)

#define CHOL_B(D, L6P, RINVP, PANEL) do {                                        \
    float A6[6][6], rinv6[6];                                                    \
    _Pragma("unroll") for (int u = 0; u < 6; ++u) {                              \
        float4 p = *(const float4*)&L6P[u * 8];                                  \
        float2 q = *(const float2*)&L6P[u * 8 + 4];                              \
        A6[u][0] = p.x; A6[u][1] = p.y; A6[u][2] = p.z; A6[u][3] = p.w;          \
        A6[u][4] = q.x; A6[u][5] = q.y;                                          \
    }                                                                            \
    _Pragma("unroll") for (int c2 = 0; c2 < 6; ++c2) rinv6[c2] = RINVP[c2];      \
    _Pragma("unroll") for (int u = 0; u < 6; ++u) {                              \
        _Pragma("unroll") for (int c2 = 0; c2 < 6; ++c2) {                       \
            float s = D[u][c2];                                                  \
            _Pragma("unroll") for (int m = 0; m < 6; ++m) if (m < c2) s -= D[u][m] * A6[c2][m]; \
            D[u][c2] = s * rinv6[c2];                                            \
        }                                                                        \
        int prow = ti * 6 + u;                                                   \
        *(float4*)&PANEL[prow * 12]     = make_float4(D[u][0], D[u][1], D[u][2], D[u][3]); \
        *(float2*)&PANEL[prow * 12 + 4] = make_float2(D[u][4], D[u][5]);         \
    }                                                                            \
} while (0)

#define CHOL_C(D, PANEL) do {                                                    \
    float pv[6][6];                                                              \
    _Pragma("unroll") for (int v = 0; v < 6; ++v) {                              \
        int prow = tj * 6 + v;                                                   \
        float4 p = *(const float4*)&PANEL[prow * 12];                            \
        float2 q = *(const float2*)&PANEL[prow * 12 + 4];                        \
        pv[v][0] = p.x; pv[v][1] = p.y; pv[v][2] = p.z; pv[v][3] = p.w;          \
        pv[v][4] = q.x; pv[v][5] = q.y;                                          \
    }                                                                            \
    _Pragma("unroll") for (int u = 0; u < 6; ++u) {                              \
        int prow = ti * 6 + u;                                                   \
        float4 p = *(const float4*)&PANEL[prow * 12];                            \
        float2 q = *(const float2*)&PANEL[prow * 12 + 4];                        \
        float pu0 = p.x, pu1 = p.y, pu2 = p.z, pu3 = p.w, pu4 = q.x, pu5 = q.y;  \
        _Pragma("unroll") for (int v = 0; v < 6; ++v) {                          \
            float s = D[u][v];                                                   \
            s = fmaf(-pu0, pv[v][0], s);                                         \
            s = fmaf(-pu1, pv[v][1], s);                                         \
            s = fmaf(-pu2, pv[v][2], s);                                         \
            s = fmaf(-pu3, pv[v][3], s);                                         \
            s = fmaf(-pu4, pv[v][4], s);                                         \
            s = fmaf(-pu5, pv[v][5], s);                                         \
            D[u][v] = s;                                                         \
        }                                                                        \
    }                                                                            \
} while (0)

#define CHOL_LOAD(D, GB) do {                                                    \
    _Pragma("unroll") for (int u = 0; u < 6; ++u) {                              \
        size_t rowp = (GB) + (size_t)(ti * 6 + u) * NMAT + tj * 6;               \
        _Pragma("unroll") for (int v = 0; v < 6; v += 2) {                       \
            float2 p = *(const float2*)&outG[rowp + v];                          \
            D[u][v] = p.x; D[u][v + 1] = p.y;                                    \
        }                                                                        \
    }                                                                            \
} while (0)

#define CHOL_STORE(D, GB) do {                                                   \
    _Pragma("unroll") for (int u = 0; u < 6; ++u) {                              \
        const int i2 = ti * 6 + u;                                               \
        size_t rowp = (GB) + (size_t)i2 * NMAT + tj * 6;                         \
        _Pragma("unroll") for (int v = 0; v < 6; v += 2) {                       \
            int j0 = tj * 6 + v;                                                 \
            float a0 = D[u][v], a1 = D[u][v + 1];                                \
            if (ti < tj) { a0 = 0.0f; a1 = 0.0f; }                               \
            else if (ti == tj) {                                                 \
                if (j0 > i2)     a0 = 0.0f;                                      \
                if (j0 + 1 > i2) a1 = 0.0f;                                      \
            }                                                                    \
            *(float2*)&outL[rowp + v] = make_float2(a0, a1);                     \
        }                                                                        \
    }                                                                            \
} while (0)

__launch_bounds__(256)
__global__ void chol_kernel(const float* __restrict__ outG,
                            float* __restrict__ outL)
{
    const int t = threadIdx.x;
    const int ti = t >> 4, tj = t & 15;
    const size_t gb0 = (size_t)(blockIdx.x * 2)     * (NMAT * NMAT);
    const size_t gb1 = (size_t)(blockIdx.x * 2 + 1) * (NMAT * NMAT);

    __shared__ float spanelA[NMAT * 12];
    __shared__ float spanelB[NMAT * 12];
    __shared__ float sL6A[6 * 8], sL6B[6 * 8];
    __shared__ float srinvA[6], srinvB[6];

    float accA[6][6], accB[6][6];
    CHOL_LOAD(accA, gb0);
    CHOL_LOAD(accB, gb1);

    for (int jb = 0; jb < 16; ++jb) {
        // Phase A: owner factors its own 6x6 (both matrices; independent chains)
        if (ti == jb && tj == jb) {
            CHOL_A(accA, sL6A, srinvA);
            CHOL_A(accB, sL6B, srinvB);
        }
        __syncthreads();
        // Phase B: panel solve (both matrices)
        if (tj == jb && ti > jb) {
            CHOL_B(accA, sL6A, srinvA, spanelA);
            CHOL_B(accB, sL6B, srinvB, spanelB);
        }
        __syncthreads();
        // Phase C: trailing rank-6 update (both matrices)
        if (tj > jb && ti >= tj) {
            CHOL_C(accA, spanelA);
            CHOL_C(accB, spanelB);
        }
    }

    CHOL_STORE(accA, gb0);
    CHOL_STORE(accB, gb1);
}

extern "C" void kernel_launch(void* const* d_in, const int* in_sizes, int n_in,
                              void* d_out, int out_size, void* d_ws, size_t ws_size,
                              hipStream_t stream) {
    const float* kp     = (const float*)d_in[0];
    const float* aug    = (const float*)d_in[1];
    const float* scales = (const float*)d_in[2];
    const float* nug    = (const float*)d_in[3];
    float* out = (float*)d_out;
    unsigned* ws = (unsigned*)d_ws;

    float* outG = out;
    float* outL = out + (size_t)NB * NMAT * NMAT;

    hipMemsetAsync(ws, 0xFF, 4, stream);
    minnz_kernel<<<(NB + 255) / 256, 256, 0, stream>>>(scales, ws);
    gram_kernel<<<NB, 256, 0, stream>>>(kp, aug, scales, nug, ws, out);
    chol_kernel<<<NB / 2, 256, 0, stream>>>(outG, outL);
}

// Round 13
// 978.011 us; speedup vs baseline: 2.7435x; 1.2445x over previous
//
#include <hip/hip_runtime.h>
#include <math.h>

#define N_LOCS 16384
#define START 4096
#define NB 12288
#define NMAT 96
#define KDIM 60

typedef __attribute__((ext_vector_type(8))) short short8;
typedef __attribute__((ext_vector_type(4))) float f32x4;

__global__ void minnz_kernel(const float* __restrict__ scales, unsigned* __restrict__ ws) {
    int idx = blockIdx.x * 256 + threadIdx.x;
    if (idx < NB) {
        float v = scales[START + idx];
        if (v != 0.0f) atomicMin(ws, __float_as_uint(v));
    }
}

__device__ __forceinline__ unsigned short f32_to_bf16_rne(float f, float* back) {
    unsigned u = __float_as_uint(f);
    unsigned r = (u + 0x7fffu + ((u >> 16) & 1u)) >> 16;
    *back = __uint_as_float(r << 16);
    return (unsigned short)r;
}

// ============ kernel 1: gram + transform + write g (r8-verified, unchanged) ============
__launch_bounds__(256)
__global__ void gram_kernel(const float* __restrict__ kp,
                            const float* __restrict__ aug,
                            const float* __restrict__ scales,
                            const float* __restrict__ nug,
                            const unsigned* __restrict__ ws,
                            float* __restrict__ out)
{
    const int b = blockIdx.x;
    const int t = threadIdx.x;
    const int ti = t >> 4, tj = t & 15;

    float* outG = out;                                   // [NB][96][96]
    float* outN = out + 2 * (size_t)NB * NMAT * NMAT;    // [NB]

    if (t == 0) outN[b] = nug[b];

    const size_t gbase = (size_t)b * (NMAT * NMAT);

    if (b == 0) {
        #pragma unroll
        for (int u = 0; u < 6; ++u) {
            int i = ti * 6 + u;
            #pragma unroll
            for (int v = 0; v < 6; ++v) {
                int j = tj * 6 + v;
                outG[gbase + (size_t)i * NMAT + j] = (i == j) ? 1.0f : 0.0f;
            }
        }
        return;
    }

    __shared__ char smem[37632];
    unsigned short* sxh  = (unsigned short*)smem;
    unsigned short* sxl  = (unsigned short*)(smem + 13824);
    float*          slin = (float*)smem;

    const float kp1 = kp[1], kp3 = kp[3], kp5 = kp[5], kp7 = kp[7];
    const float kp8 = kp[8], kp9 = kp[9], kp11 = kp[11];
    float sc = scales[START + b];
    if (sc == 0.0f) sc = __uint_as_float(ws[0]) * 0.5f;
    const float sigma   = __expf(kp1 + kp3 * __logf(sc));
    const float sigma2  = sigma * sigma;
    const float inv_ls2 = 1.0f / (3.0f * __expf(2.0f * kp11));
    const float inv_nug = 1.0f / nug[b];

    const int c = t & 63;
    float myscale = 0.0f;
    if (c < KDIM) {
        float kf = (c < 30) ? (float)(c + 1) : (float)(c - 29);
        float th = (c < 30) ? kp5 : kp8;
        float de = (c < 30) ? kp7 : kp9;
        myscale = __expf(th - 0.5f * __expf(de) * kf);
    }

    {
        const int rgrp = t >> 6;
        const size_t rowstride = (size_t)N_LOCS * 61;
        const size_t base = (size_t)(START + b) * 61 + 1 + c;
        for (int it = 0; it < 24; ++it) {
            int i = it * 4 + rgrp;
            float v = 0.0f;
            if (c < KDIM) {
                v = aug[base + (size_t)i * rowstride];
                v = (v != v) ? 0.0f : v;
                v *= myscale;
            }
            float fh;
            unsigned short hb = f32_to_bf16_rne(v, &fh);
            float dummy;
            unsigned short lb = f32_to_bf16_rne(v - fh, &dummy);
            sxh[i * 72 + c] = hb;
            sxl[i * 72 + c] = lb;
        }
    }
    __syncthreads();

    {
        const int w  = t >> 6;
        const int l  = t & 63;
        const int wrB = (w >> 1) * 48;
        const int wcB = (w & 1) * 48;
        const int lrow = l & 15;
        const int lk   = (l >> 4) * 8;

        f32x4 gacc[3][3];
        #pragma unroll
        for (int a = 0; a < 3; ++a)
            #pragma unroll
            for (int cc = 0; cc < 3; ++cc) gacc[a][cc] = (f32x4){0.f, 0.f, 0.f, 0.f};

        #pragma unroll
        for (int k0 = 0; k0 < 64; k0 += 32) {
            #pragma unroll
            for (int a = 0; a < 3; ++a) {
                int arow = wrB + a * 16 + lrow;
                short8 Ah = *(const short8*)&sxh[arow * 72 + k0 + lk];
                short8 Al = *(const short8*)&sxl[arow * 72 + k0 + lk];
                #pragma unroll
                for (int cc = 0; cc < 3; ++cc) {
                    int brow = wcB + cc * 16 + lrow;
                    short8 Bh = *(const short8*)&sxh[brow * 72 + k0 + lk];
                    short8 Bl = *(const short8*)&sxl[brow * 72 + k0 + lk];
                    gacc[a][cc] = __builtin_amdgcn_mfma_f32_16x16x32_bf16(Ah, Bh, gacc[a][cc], 0, 0, 0);
                    gacc[a][cc] = __builtin_amdgcn_mfma_f32_16x16x32_bf16(Ah, Bl, gacc[a][cc], 0, 0, 0);
                    gacc[a][cc] = __builtin_amdgcn_mfma_f32_16x16x32_bf16(Al, Bh, gacc[a][cc], 0, 0, 0);
                    gacc[a][cc] = __builtin_amdgcn_mfma_f32_16x16x32_bf16(Al, Bl, gacc[a][cc], 0, 0, 0);
                }
            }
        }
        __syncthreads();

        #pragma unroll
        for (int a = 0; a < 3; ++a)
            #pragma unroll
            for (int cc = 0; cc < 3; ++cc) {
                int col = wcB + cc * 16 + lrow;
                #pragma unroll
                for (int r = 0; r < 4; ++r) {
                    int row = wrB + a * 16 + (l >> 4) * 4 + r;
                    slin[row * 98 + col] = gacc[a][cc][r];
                }
            }
    }
    __syncthreads();

    float acc[6][6];
    #pragma unroll
    for (int u = 0; u < 6; ++u) {
        int rb = (ti * 6 + u) * 98;
        #pragma unroll
        for (int v = 0; v < 6; v += 2) {
            float2 p = *(const float2*)&slin[rb + tj * 6 + v];
            acc[u][v] = p.x; acc[u][v + 1] = p.y;
        }
    }
    float di[6], dj[6];
    #pragma unroll
    for (int u = 0; u < 6; ++u) { int i = ti * 6 + u; di[u] = slin[i * 98 + i]; }
    #pragma unroll
    for (int v = 0; v < 6; ++v) { int j = tj * 6 + v; dj[v] = slin[j * 98 + j]; }

    #pragma unroll
    for (int u = 0; u < 6; ++u) {
        int i = ti * 6 + u;
        #pragma unroll
        for (int v = 0; v < 6; ++v) {
            int j = tj * 6 + v;
            float lin = acc[u][v];
            float d2 = (di[u] + dj[v] - 2.0f * lin) * inv_ls2;
            d2 = fmaxf(d2, 0.0f);
            float cc = sqrtf(3.0f * d2);
            float nl = (1.0f + cc) * __expf(-cc);
            acc[u][v] = fmaf(sigma2, nl, lin) * inv_nug + ((i == j) ? 1.0f : 0.0f);
        }
    }
    #pragma unroll
    for (int u = 0; u < 6; ++u) {
        size_t row = gbase + (size_t)(ti * 6 + u) * NMAT + tj * 6;
        #pragma unroll
        for (int v = 0; v < 6; v += 2) {
            *(float2*)&outG[row + v] = make_float2(acc[u][v], acc[u][v + 1]);
        }
    }
}

// ====== kernel 2: WAVE-PER-MATRIX cholesky — r11 VERBATIM dataflow, ROLLED loop ======
// r11 (fully unrolled) PASSED correctness but ran at 14% VALUBusy: ~176KB of
// unrolled code streamed through the 32KB L1I. This version is byte-identical in
// dataflow/arithmetic; only the jb loop is kept rolled (#pragma unroll 1) so the
// body (~16KB) fits I-cache. All register indices in the macros remain
// compile-time (u/v/m inner loops unrolled); J appears only in lane compares and
// LDS addressing.

#define PHASE_A(D) do {                                                          \
    _Pragma("unroll") for (int c2 = 0; c2 < 6; ++c2) {                           \
        float s = D[c2][c2];                                                     \
        _Pragma("unroll") for (int m = 0; m < 6; ++m) if (m < c2) s -= D[c2][m] * D[c2][m]; \
        float l = sqrtf(s);                                                      \
        D[c2][c2] = l;                                                           \
        float rinv = 1.0f / l;                                                   \
        rinvp[c2] = rinv;                                                        \
        _Pragma("unroll") for (int rr = 0; rr < 6; ++rr) if (rr > c2) {          \
            float s2 = D[rr][c2];                                                \
            _Pragma("unroll") for (int m = 0; m < 6; ++m) if (m < c2) s2 -= D[rr][m] * D[c2][m]; \
            D[rr][c2] = s2 * rinv;                                               \
        }                                                                        \
    }                                                                            \
    _Pragma("unroll") for (int u = 0; u < 6; ++u) {                              \
        *(float4*)&L6p[u * 8]     = make_float4(D[u][0], D[u][1], D[u][2], D[u][3]); \
        *(float2*)&L6p[u * 8 + 4] = make_float2(D[u][4], D[u][5]);               \
    }                                                                            \
} while (0)

#define PHASE_B(D, TIEFF) do {                                                   \
    float A6[6][6], rinv6[6];                                                    \
    _Pragma("unroll") for (int u = 0; u < 6; ++u) {                              \
        float4 p = *(const float4*)&L6p[u * 8];                                  \
        float2 q = *(const float2*)&L6p[u * 8 + 4];                              \
        A6[u][0] = p.x; A6[u][1] = p.y; A6[u][2] = p.z; A6[u][3] = p.w;          \
        A6[u][4] = q.x; A6[u][5] = q.y;                                          \
    }                                                                            \
    _Pragma("unroll") for (int c2 = 0; c2 < 6; ++c2) rinv6[c2] = rinvp[c2];      \
    _Pragma("unroll") for (int u = 0; u < 6; ++u) {                              \
        _Pragma("unroll") for (int c2 = 0; c2 < 6; ++c2) {                       \
            float s = D[u][c2];                                                  \
            _Pragma("unroll") for (int m = 0; m < 6; ++m) if (m < c2) s -= D[u][m] * A6[c2][m]; \
            D[u][c2] = s * rinv6[c2];                                            \
        }                                                                        \
        int prow = (TIEFF) * 6 + u;                                              \
        *(float4*)&panel[prow * 12]     = make_float4(D[u][0], D[u][1], D[u][2], D[u][3]); \
        *(float2*)&panel[prow * 12 + 4] = make_float2(D[u][4], D[u][5]);         \
    }                                                                            \
} while (0)

#define PHASE_C(D, TIEFF, TJEFF) do {                                            \
    float pv[6][6];                                                              \
    _Pragma("unroll") for (int v = 0; v < 6; ++v) {                              \
        int prow = (TJEFF) * 6 + v;                                              \
        float4 p = *(const float4*)&panel[prow * 12];                            \
        float2 q = *(const float2*)&panel[prow * 12 + 4];                        \
        pv[v][0] = p.x; pv[v][1] = p.y; pv[v][2] = p.z; pv[v][3] = p.w;          \
        pv[v][4] = q.x; pv[v][5] = q.y;                                          \
    }                                                                            \
    _Pragma("unroll") for (int u = 0; u < 6; ++u) {                              \
        int prow = (TIEFF) * 6 + u;                                              \
        float4 p = *(const float4*)&panel[prow * 12];                            \
        float2 q = *(const float2*)&panel[prow * 12 + 4];                        \
        float pu0 = p.x, pu1 = p.y, pu2 = p.z, pu3 = p.w, pu4 = q.x, pu5 = q.y;  \
        _Pragma("unroll") for (int v = 0; v < 6; ++v) {                          \
            float s = D[u][v];                                                   \
            s = fmaf(-pu0, pv[v][0], s);                                         \
            s = fmaf(-pu1, pv[v][1], s);                                         \
            s = fmaf(-pu2, pv[v][2], s);                                         \
            s = fmaf(-pu3, pv[v][3], s);                                         \
            s = fmaf(-pu4, pv[v][4], s);                                         \
            s = fmaf(-pu5, pv[v][5], s);                                         \
            D[u][v] = s;                                                         \
        }                                                                        \
    }                                                                            \
} while (0)

#define STORE_TILE(D, TIEFF, TJEFF) do {                                         \
    _Pragma("unroll") for (int u = 0; u < 6; ++u) {                              \
        const int i2 = (TIEFF) * 6 + u;                                          \
        size_t rowp = gbase + (size_t)i2 * NMAT + (TJEFF) * 6;                   \
        _Pragma("unroll") for (int v = 0; v < 6; v += 2) {                       \
            int j0 = (TJEFF) * 6 + v;                                            \
            float a0 = D[u][v], a1 = D[u][v + 1];                                \
            if ((TIEFF) < (TJEFF)) { a0 = 0.0f; a1 = 0.0f; }                     \
            else if ((TIEFF) == (TJEFF)) {                                       \
                if (j0 > i2)     a0 = 0.0f;                                      \
                if (j0 + 1 > i2) a1 = 0.0f;                                      \
            }                                                                    \
            *(float2*)&outL[rowp + v] = make_float2(a0, a1);                     \
        }                                                                        \
    }                                                                            \
} while (0)

#define LOAD_TILE(D, TIEFF, TJEFF) do {                                          \
    _Pragma("unroll") for (int u = 0; u < 6; ++u) {                              \
        size_t rowp = gbase + (size_t)((TIEFF) * 6 + u) * NMAT + (TJEFF) * 6;    \
        float2 p0 = *(const float2*)&outG[rowp + 0];                             \
        float2 p1 = *(const float2*)&outG[rowp + 2];                             \
        float2 p2 = *(const float2*)&outG[rowp + 4];                             \
        D[u][0] = p0.x; D[u][1] = p0.y; D[u][2] = p1.x;                          \
        D[u][3] = p1.y; D[u][4] = p2.x; D[u][5] = p2.y;                          \
    }                                                                            \
} while (0)

__launch_bounds__(256)
__global__ void chol_kernel(const float* __restrict__ outG,
                            float* __restrict__ outL)
{
    const int w    = threadIdx.x >> 6;   // wave id 0..3 -> matrix
    const int lane = threadIdx.x & 63;
    const int wi   = lane >> 3;          // 0..7 row-tile
    const int wj   = lane & 7;           // 0..7 col-tile
    const int b    = blockIdx.x * 4 + w;
    const size_t gbase = (size_t)b * (NMAT * NMAT);

    __shared__ float spanel_all[4][96][12];
    __shared__ float sL6_all[4][6][8];
    __shared__ float srinv_all[4][8];
    float* panel = &spanel_all[w][0][0];
    float* L6p   = &sL6_all[w][0][0];
    float* rinvp = &srinv_all[w][0];

    float acc00[6][6], acc10[6][6], acc11[6][6];

    LOAD_TILE(acc00, wi,     wj);
    LOAD_TILE(acc10, 8 + wi, wj);
    LOAD_TILE(acc11, 8 + wi, 8 + wj);

    #pragma unroll 1
    for (int jb = 0; jb < 8; ++jb) {
        const int J = jb;
        // Phase A: owner tile (jb,jb) = T00 of lane (J,J)
        if (wi == J && wj == J) PHASE_A(acc00);
        // Phase B: column jb
        if (wj == J && wi > J) PHASE_B(acc00, wi);
        if (wj == J)           PHASE_B(acc10, 8 + wi);   // ti=8+wi > jb always
        // Phase C: trailing update
        if (wj > J && wi >= wj) PHASE_C(acc00, wi, wj);
        if (wj > J)             PHASE_C(acc10, 8 + wi, wj);       // ti>=tj always
        if (wi >= wj)           PHASE_C(acc11, 8 + wi, 8 + wj);   // tj>jb always
    }
    #pragma unroll 1
    for (int jb = 8; jb < 16; ++jb) {
        const int J = jb - 8;
        // Phase A: owner tile (jb,jb) = T11 of lane (J,J)
        if (wi == J && wj == J) PHASE_A(acc11);
        // Phase B
        if (wj == J && wi > J) PHASE_B(acc11, 8 + wi);
        // Phase C
        if (wj > J && wi >= wj) PHASE_C(acc11, 8 + wi, 8 + wj);
    }

    // ---- write L: three computed quadrant slots + zero upper-right quadrant ----
    STORE_TILE(acc00, wi,     wj);
    STORE_TILE(acc10, 8 + wi, wj);
    STORE_TILE(acc11, 8 + wi, 8 + wj);
    #pragma unroll
    for (int u = 0; u < 6; ++u) {
        size_t rowp = gbase + (size_t)(wi * 6 + u) * NMAT + (8 + wj) * 6;
        *(float2*)&outL[rowp + 0] = make_float2(0.0f, 0.0f);
        *(float2*)&outL[rowp + 2] = make_float2(0.0f, 0.0f);
        *(float2*)&outL[rowp + 4] = make_float2(0.0f, 0.0f);
    }
}

extern "C" void kernel_launch(void* const* d_in, const int* in_sizes, int n_in,
                              void* d_out, int out_size, void* d_ws, size_t ws_size,
                              hipStream_t stream) {
    const float* kp     = (const float*)d_in[0];
    const float* aug    = (const float*)d_in[1];
    const float* scales = (const float*)d_in[2];
    const float* nug    = (const float*)d_in[3];
    float* out = (float*)d_out;
    unsigned* ws = (unsigned*)d_ws;

    float* outG = out;
    float* outL = out + (size_t)NB * NMAT * NMAT;

    hipMemsetAsync(ws, 0xFF, 4, stream);
    minnz_kernel<<<(NB + 255) / 256, 256, 0, stream>>>(scales, ws);
    gram_kernel<<<NB, 256, 0, stream>>>(kp, aug, scales, nug, ws, out);
    chol_kernel<<<NB / 4, 256, 0, stream>>>(outG, outL);
}

// Round 16
// 952.087 us; speedup vs baseline: 2.8182x; 1.0272x over previous
//
#include <hip/hip_runtime.h>
#include <math.h>

#define N_LOCS 16384
#define START 4096
#define NB 12288
#define NMAT 96
#define KDIM 60

typedef __attribute__((ext_vector_type(8))) short short8;
typedef __attribute__((ext_vector_type(4))) float f32x4;

__global__ void minnz_kernel(const float* __restrict__ scales, unsigned* __restrict__ ws) {
    int idx = blockIdx.x * 256 + threadIdx.x;
    if (idx < NB) {
        float v = scales[START + idx];
        if (v != 0.0f) atomicMin(ws, __float_as_uint(v));
    }
}

__device__ __forceinline__ unsigned short f32_to_bf16_rne(float f, float* back) {
    unsigned u = __float_as_uint(f);
    unsigned r = (u + 0x7fffu + ((u >> 16) & 1u)) >> 16;
    *back = __uint_as_float(r << 16);
    return (unsigned short)r;
}

// ============ kernel 1: gram + transform + write g (r8-verified, unchanged) ============
__launch_bounds__(256)
__global__ void gram_kernel(const float* __restrict__ kp,
                            const float* __restrict__ aug,
                            const float* __restrict__ scales,
                            const float* __restrict__ nug,
                            const unsigned* __restrict__ ws,
                            float* __restrict__ out)
{
    const int b = blockIdx.x;
    const int t = threadIdx.x;
    const int ti = t >> 4, tj = t & 15;

    float* outG = out;                                   // [NB][96][96]
    float* outN = out + 2 * (size_t)NB * NMAT * NMAT;    // [NB]

    if (t == 0) outN[b] = nug[b];

    const size_t gbase = (size_t)b * (NMAT * NMAT);

    if (b == 0) {
        #pragma unroll
        for (int u = 0; u < 6; ++u) {
            int i = ti * 6 + u;
            #pragma unroll
            for (int v = 0; v < 6; ++v) {
                int j = tj * 6 + v;
                outG[gbase + (size_t)i * NMAT + j] = (i == j) ? 1.0f : 0.0f;
            }
        }
        return;
    }

    __shared__ char smem[37632];
    unsigned short* sxh  = (unsigned short*)smem;
    unsigned short* sxl  = (unsigned short*)(smem + 13824);
    float*          slin = (float*)smem;

    const float kp1 = kp[1], kp3 = kp[3], kp5 = kp[5], kp7 = kp[7];
    const float kp8 = kp[8], kp9 = kp[9], kp11 = kp[11];
    float sc = scales[START + b];
    if (sc == 0.0f) sc = __uint_as_float(ws[0]) * 0.5f;
    const float sigma   = __expf(kp1 + kp3 * __logf(sc));
    const float sigma2  = sigma * sigma;
    const float inv_ls2 = 1.0f / (3.0f * __expf(2.0f * kp11));
    const float inv_nug = 1.0f / nug[b];

    const int c = t & 63;
    float myscale = 0.0f;
    if (c < KDIM) {
        float kf = (c < 30) ? (float)(c + 1) : (float)(c - 29);
        float th = (c < 30) ? kp5 : kp8;
        float de = (c < 30) ? kp7 : kp9;
        myscale = __expf(th - 0.5f * __expf(de) * kf);
    }

    {
        const int rgrp = t >> 6;
        const size_t rowstride = (size_t)N_LOCS * 61;
        const size_t base = (size_t)(START + b) * 61 + 1 + c;
        for (int it = 0; it < 24; ++it) {
            int i = it * 4 + rgrp;
            float v = 0.0f;
            if (c < KDIM) {
                v = aug[base + (size_t)i * rowstride];
                v = (v != v) ? 0.0f : v;
                v *= myscale;
            }
            float fh;
            unsigned short hb = f32_to_bf16_rne(v, &fh);
            float dummy;
            unsigned short lb = f32_to_bf16_rne(v - fh, &dummy);
            sxh[i * 72 + c] = hb;
            sxl[i * 72 + c] = lb;
        }
    }
    __syncthreads();

    {
        const int w  = t >> 6;
        const int l  = t & 63;
        const int wrB = (w >> 1) * 48;
        const int wcB = (w & 1) * 48;
        const int lrow = l & 15;
        const int lk   = (l >> 4) * 8;

        f32x4 gacc[3][3];
        #pragma unroll
        for (int a = 0; a < 3; ++a)
            #pragma unroll
            for (int cc = 0; cc < 3; ++cc) gacc[a][cc] = (f32x4){0.f, 0.f, 0.f, 0.f};

        #pragma unroll
        for (int k0 = 0; k0 < 64; k0 += 32) {
            #pragma unroll
            for (int a = 0; a < 3; ++a) {
                int arow = wrB + a * 16 + lrow;
                short8 Ah = *(const short8*)&sxh[arow * 72 + k0 + lk];
                short8 Al = *(const short8*)&sxl[arow * 72 + k0 + lk];
                #pragma unroll
                for (int cc = 0; cc < 3; ++cc) {
                    int brow = wcB + cc * 16 + lrow;
                    short8 Bh = *(const short8*)&sxh[brow * 72 + k0 + lk];
                    short8 Bl = *(const short8*)&sxl[brow * 72 + k0 + lk];
                    gacc[a][cc] = __builtin_amdgcn_mfma_f32_16x16x32_bf16(Ah, Bh, gacc[a][cc], 0, 0, 0);
                    gacc[a][cc] = __builtin_amdgcn_mfma_f32_16x16x32_bf16(Ah, Bl, gacc[a][cc], 0, 0, 0);
                    gacc[a][cc] = __builtin_amdgcn_mfma_f32_16x16x32_bf16(Al, Bh, gacc[a][cc], 0, 0, 0);
                    gacc[a][cc] = __builtin_amdgcn_mfma_f32_16x16x32_bf16(Al, Bl, gacc[a][cc], 0, 0, 0);
                }
            }
        }
        __syncthreads();

        #pragma unroll
        for (int a = 0; a < 3; ++a)
            #pragma unroll
            for (int cc = 0; cc < 3; ++cc) {
                int col = wcB + cc * 16 + lrow;
                #pragma unroll
                for (int r = 0; r < 4; ++r) {
                    int row = wrB + a * 16 + (l >> 4) * 4 + r;
                    slin[row * 98 + col] = gacc[a][cc][r];
                }
            }
    }
    __syncthreads();

    float acc[6][6];
    #pragma unroll
    for (int u = 0; u < 6; ++u) {
        int rb = (ti * 6 + u) * 98;
        #pragma unroll
        for (int v = 0; v < 6; v += 2) {
            float2 p = *(const float2*)&slin[rb + tj * 6 + v];
            acc[u][v] = p.x; acc[u][v + 1] = p.y;
        }
    }
    float di[6], dj[6];
    #pragma unroll
    for (int u = 0; u < 6; ++u) { int i = ti * 6 + u; di[u] = slin[i * 98 + i]; }
    #pragma unroll
    for (int v = 0; v < 6; ++v) { int j = tj * 6 + v; dj[v] = slin[j * 98 + j]; }

    #pragma unroll
    for (int u = 0; u < 6; ++u) {
        int i = ti * 6 + u;
        #pragma unroll
        for (int v = 0; v < 6; ++v) {
            int j = tj * 6 + v;
            float lin = acc[u][v];
            float d2 = (di[u] + dj[v] - 2.0f * lin) * inv_ls2;
            d2 = fmaxf(d2, 0.0f);
            float cc = sqrtf(3.0f * d2);
            float nl = (1.0f + cc) * __expf(-cc);
            acc[u][v] = fmaf(sigma2, nl, lin) * inv_nug + ((i == j) ? 1.0f : 0.0f);
        }
    }
    #pragma unroll
    for (int u = 0; u < 6; ++u) {
        size_t row = gbase + (size_t)(ti * 6 + u) * NMAT + tj * 6;
        #pragma unroll
        for (int v = 0; v < 6; v += 2) {
            *(float2*)&outG[row + v] = make_float2(acc[u][v], acc[u][v + 1]);
        }
    }
}

// ====== kernel 2: WAVE-PER-MATRIX cholesky — r13 STRUCTURE VERBATIM (256 thr, ======
// ====== 4 waves, grid NB/4, rolled loops). ONLY change vs r13: register-light ======
// ====== PHASE_B (c2-outer) and PHASE_C (m-outer). Bitwise-identical values:  ======
// ====== every element receives its fma contributions in the same m-ascending ======
// ====== order as r13's bodies.                                               ======

#define PHASE_A(D) do {                                                          \
    _Pragma("unroll") for (int c2 = 0; c2 < 6; ++c2) {                           \
        float s = D[c2][c2];                                                     \
        _Pragma("unroll") for (int m = 0; m < 6; ++m) if (m < c2) s -= D[c2][m] * D[c2][m]; \
        float l = sqrtf(s);                                                      \
        D[c2][c2] = l;                                                           \
        float rinv = 1.0f / l;                                                   \
        rinvp[c2] = rinv;                                                        \
        _Pragma("unroll") for (int rr = 0; rr < 6; ++rr) if (rr > c2) {          \
            float s2 = D[rr][c2];                                                \
            _Pragma("unroll") for (int m = 0; m < 6; ++m) if (m < c2) s2 -= D[rr][m] * D[c2][m]; \
            D[rr][c2] = s2 * rinv;                                               \
        }                                                                        \
    }                                                                            \
    _Pragma("unroll") for (int u = 0; u < 6; ++u) {                              \
        *(float4*)&L6p[u * 8]     = make_float4(D[u][0], D[u][1], D[u][2], D[u][3]); \
        *(float2*)&L6p[u * 8 + 4] = make_float2(D[u][4], D[u][5]);               \
    }                                                                            \
} while (0)

// c2-outer panel solve: one L6 row (6 regs) live at a time. Per-element fma
// order (m ascending) identical to the u-outer form -> bitwise same values.
#define PHASE_B(D, TIEFF) do {                                                   \
    _Pragma("unroll") for (int c2 = 0; c2 < 6; ++c2) {                           \
        float4 p = *(const float4*)&L6p[c2 * 8];                                 \
        float2 q = *(const float2*)&L6p[c2 * 8 + 4];                             \
        float a0 = p.x, a1 = p.y, a2 = p.z, a3 = p.w, a4 = q.x;                  \
        (void)q;                                                                 \
        float rinv = rinvp[c2];                                                  \
        _Pragma("unroll") for (int u = 0; u < 6; ++u) {                          \
            float s = D[u][c2];                                                  \
            if (c2 > 0) s -= D[u][0] * a0;                                       \
            if (c2 > 1) s -= D[u][1] * a1;                                       \
            if (c2 > 2) s -= D[u][2] * a2;                                       \
            if (c2 > 3) s -= D[u][3] * a3;                                       \
            if (c2 > 4) s -= D[u][4] * a4;                                       \
            D[u][c2] = s * rinv;                                                 \
        }                                                                        \
    }                                                                            \
    _Pragma("unroll") for (int u = 0; u < 6; ++u) {                              \
        int prow = (TIEFF) * 6 + u;                                              \
        *(float4*)&panel[prow * 12]     = make_float4(D[u][0], D[u][1], D[u][2], D[u][3]); \
        *(float2*)&panel[prow * 12 + 4] = make_float2(D[u][4], D[u][5]);         \
    }                                                                            \
} while (0)

// m-outer trailing update: pum[6]+pvm[6] = 12 temp regs. Each D[u][v] receives
// its 6 fma contributions in m=0..5 order, same as r13's body -> bitwise same.
// pum loads broadcast across lanes sharing wi; pvm across lanes sharing wj.
#define PHASE_C(D, TIEFF, TJEFF) do {                                            \
    _Pragma("unroll") for (int m = 0; m < 6; ++m) {                              \
        float pum[6], pvm[6];                                                    \
        _Pragma("unroll") for (int u = 0; u < 6; ++u)                            \
            pum[u] = panel[((TIEFF) * 6 + u) * 12 + m];                          \
        _Pragma("unroll") for (int v = 0; v < 6; ++v)                            \
            pvm[v] = panel[((TJEFF) * 6 + v) * 12 + m];                          \
        _Pragma("unroll") for (int u = 0; u < 6; ++u)                            \
            _Pragma("unroll") for (int v = 0; v < 6; ++v)                        \
                D[u][v] = fmaf(-pum[u], pvm[v], D[u][v]);                        \
    }                                                                            \
} while (0)

#define STORE_TILE(D, TIEFF, TJEFF) do {                                         \
    _Pragma("unroll") for (int u = 0; u < 6; ++u) {                              \
        const int i2 = (TIEFF) * 6 + u;                                          \
        size_t rowp = gbase + (size_t)i2 * NMAT + (TJEFF) * 6;                   \
        _Pragma("unroll") for (int v = 0; v < 6; v += 2) {                       \
            int j0 = (TJEFF) * 6 + v;                                            \
            float a0 = D[u][v], a1 = D[u][v + 1];                                \
            if ((TIEFF) < (TJEFF)) { a0 = 0.0f; a1 = 0.0f; }                     \
            else if ((TIEFF) == (TJEFF)) {                                       \
                if (j0 > i2)     a0 = 0.0f;                                      \
                if (j0 + 1 > i2) a1 = 0.0f;                                      \
            }                                                                    \
            *(float2*)&outL[rowp + v] = make_float2(a0, a1);                     \
        }                                                                        \
    }                                                                            \
} while (0)

#define LOAD_TILE(D, TIEFF, TJEFF) do {                                          \
    _Pragma("unroll") for (int u = 0; u < 6; ++u) {                              \
        size_t rowp = gbase + (size_t)((TIEFF) * 6 + u) * NMAT + (TJEFF) * 6;    \
        float2 p0 = *(const float2*)&outG[rowp + 0];                             \
        float2 p1 = *(const float2*)&outG[rowp + 2];                             \
        float2 p2 = *(const float2*)&outG[rowp + 4];                             \
        D[u][0] = p0.x; D[u][1] = p0.y; D[u][2] = p1.x;                          \
        D[u][3] = p1.y; D[u][4] = p2.x; D[u][5] = p2.y;                          \
    }                                                                            \
} while (0)

__launch_bounds__(256)
__global__ void chol_kernel(const float* __restrict__ outG,
                            float* __restrict__ outL)
{
    const int w    = threadIdx.x >> 6;   // wave id 0..3 -> matrix
    const int lane = threadIdx.x & 63;
    const int wi   = lane >> 3;          // 0..7 row-tile
    const int wj   = lane & 7;           // 0..7 col-tile
    const int b    = blockIdx.x * 4 + w;
    const size_t gbase = (size_t)b * (NMAT * NMAT);

    __shared__ float spanel_all[4][96][12];
    __shared__ float sL6_all[4][6][8];
    __shared__ float srinv_all[4][8];
    float* panel = &spanel_all[w][0][0];
    float* L6p   = &sL6_all[w][0][0];
    float* rinvp = &srinv_all[w][0];

    float acc00[6][6], acc10[6][6], acc11[6][6];

    LOAD_TILE(acc00, wi,     wj);
    LOAD_TILE(acc10, 8 + wi, wj);
    LOAD_TILE(acc11, 8 + wi, 8 + wj);

    #pragma unroll 1
    for (int jb = 0; jb < 8; ++jb) {
        const int J = jb;
        // Phase A: owner tile (jb,jb) = T00 of lane (J,J)
        if (wi == J && wj == J) PHASE_A(acc00);
        // Phase B: column jb
        if (wj == J && wi > J) PHASE_B(acc00, wi);
        if (wj == J)           PHASE_B(acc10, 8 + wi);   // ti=8+wi > jb always
        // Phase C: trailing update
        if (wj > J && wi >= wj) PHASE_C(acc00, wi, wj);
        if (wj > J)             PHASE_C(acc10, 8 + wi, wj);       // ti>=tj always
        if (wi >= wj)           PHASE_C(acc11, 8 + wi, 8 + wj);   // tj>jb always
    }
    #pragma unroll 1
    for (int jb = 8; jb < 16; ++jb) {
        const int J = jb - 8;
        // Phase A: owner tile (jb,jb) = T11 of lane (J,J)
        if (wi == J && wj == J) PHASE_A(acc11);
        // Phase B
        if (wj == J && wi > J) PHASE_B(acc11, 8 + wi);
        // Phase C
        if (wj > J && wi >= wj) PHASE_C(acc11, 8 + wi, 8 + wj);
    }

    // ---- write L: three computed quadrant slots + zero upper-right quadrant ----
    STORE_TILE(acc00, wi,     wj);
    STORE_TILE(acc10, 8 + wi, wj);
    STORE_TILE(acc11, 8 + wi, 8 + wj);
    #pragma unroll
    for (int u = 0; u < 6; ++u) {
        size_t rowp = gbase + (size_t)(wi * 6 + u) * NMAT + (8 + wj) * 6;
        *(float2*)&outL[rowp + 0] = make_float2(0.0f, 0.0f);
        *(float2*)&outL[rowp + 2] = make_float2(0.0f, 0.0f);
        *(float2*)&outL[rowp + 4] = make_float2(0.0f, 0.0f);
    }
}

extern "C" void kernel_launch(void* const* d_in, const int* in_sizes, int n_in,
                              void* d_out, int out_size, void* d_ws, size_t ws_size,
                              hipStream_t stream) {
    const float* kp     = (const float*)d_in[0];
    const float* aug    = (const float*)d_in[1];
    const float* scales = (const float*)d_in[2];
    const float* nug    = (const float*)d_in[3];
    float* out = (float*)d_out;
    unsigned* ws = (unsigned*)d_ws;

    float* outG = out;
    float* outL = out + (size_t)NB * NMAT * NMAT;

    hipMemsetAsync(ws, 0xFF, 4, stream);
    minnz_kernel<<<(NB + 255) / 256, 256, 0, stream>>>(scales, ws);
    gram_kernel<<<NB, 256, 0, stream>>>(kp, aug, scales, nug, ws, out);
    chol_kernel<<<NB / 4, 256, 0, stream>>>(outG, outL);
}

// Round 18
// 824.512 us; speedup vs baseline: 3.2543x; 1.1547x over previous
//
#include <hip/hip_runtime.h>
#include <math.h>

#define N_LOCS 16384
#define START 4096
#define NB 12288
#define NMAT 96
#define KDIM 60

typedef __attribute__((ext_vector_type(8))) short short8;
typedef __attribute__((ext_vector_type(4))) float f32x4;

__global__ void minnz_kernel(const float* __restrict__ scales, unsigned* __restrict__ ws) {
    int idx = blockIdx.x * 256 + threadIdx.x;
    if (idx < NB) {
        float v = scales[START + idx];
        if (v != 0.0f) atomicMin(ws, __float_as_uint(v));
    }
}

__device__ __forceinline__ unsigned short f32_to_bf16_rne(float f, float* back) {
    unsigned u = __float_as_uint(f);
    unsigned r = (u + 0x7fffu + ((u >> 16) & 1u)) >> 16;
    *back = __uint_as_float(r << 16);
    return (unsigned short)r;
}

// ============ kernel 1: gram + transform + write g ============
// Only change vs r16 (never-NaN'd kernel): staging loads batched 12-deep into
// registers before convert+LDS-write (breaks the 24x load-use latency chain).
// Per-element value sequence (load -> NaN-clean -> *myscale -> bf16 split)
// unchanged -> bitwise-identical g.
__launch_bounds__(256)
__global__ void gram_kernel(const float* __restrict__ kp,
                            const float* __restrict__ aug,
                            const float* __restrict__ scales,
                            const float* __restrict__ nug,
                            const unsigned* __restrict__ ws,
                            float* __restrict__ out)
{
    const int b = blockIdx.x;
    const int t = threadIdx.x;
    const int ti = t >> 4, tj = t & 15;

    float* outG = out;                                   // [NB][96][96]
    float* outN = out + 2 * (size_t)NB * NMAT * NMAT;    // [NB]

    if (t == 0) outN[b] = nug[b];

    const size_t gbase = (size_t)b * (NMAT * NMAT);

    if (b == 0) {
        #pragma unroll
        for (int u = 0; u < 6; ++u) {
            int i = ti * 6 + u;
            #pragma unroll
            for (int v = 0; v < 6; ++v) {
                int j = tj * 6 + v;
                outG[gbase + (size_t)i * NMAT + j] = (i == j) ? 1.0f : 0.0f;
            }
        }
        return;
    }

    __shared__ char smem[37632];
    unsigned short* sxh  = (unsigned short*)smem;
    unsigned short* sxl  = (unsigned short*)(smem + 13824);
    float*          slin = (float*)smem;

    const float kp1 = kp[1], kp3 = kp[3], kp5 = kp[5], kp7 = kp[7];
    const float kp8 = kp[8], kp9 = kp[9], kp11 = kp[11];
    float sc = scales[START + b];
    if (sc == 0.0f) sc = __uint_as_float(ws[0]) * 0.5f;
    const float sigma   = __expf(kp1 + kp3 * __logf(sc));
    const float sigma2  = sigma * sigma;
    const float inv_ls2 = 1.0f / (3.0f * __expf(2.0f * kp11));
    const float inv_nug = 1.0f / nug[b];

    const int c = t & 63;
    float myscale = 0.0f;
    if (c < KDIM) {
        float kf = (c < 30) ? (float)(c + 1) : (float)(c - 29);
        float th = (c < 30) ? kp5 : kp8;
        float de = (c < 30) ? kp7 : kp9;
        myscale = __expf(th - 0.5f * __expf(de) * kf);
    }

    // ---- stage x into LDS as split-bf16; 12-deep register prefetch batches ----
    {
        const int rgrp = t >> 6;
        const size_t rowstride = (size_t)N_LOCS * 61;
        const size_t base = (size_t)(START + b) * 61 + 1 + c;
        #pragma unroll
        for (int half = 0; half < 2; ++half) {
            float vb[12];
            #pragma unroll
            for (int it = 0; it < 12; ++it) {
                int i = (half * 12 + it) * 4 + rgrp;
                vb[it] = (c < KDIM) ? aug[base + (size_t)i * rowstride] : 0.0f;
            }
            #pragma unroll
            for (int it = 0; it < 12; ++it) {
                int i = (half * 12 + it) * 4 + rgrp;
                float v = vb[it];
                v = (v != v) ? 0.0f : v;
                v *= myscale;
                float fh;
                unsigned short hb = f32_to_bf16_rne(v, &fh);
                float dummy;
                unsigned short lb = f32_to_bf16_rne(v - fh, &dummy);
                sxh[i * 72 + c] = hb;
                sxl[i * 72 + c] = lb;
            }
        }
    }
    __syncthreads();

    {
        const int w  = t >> 6;
        const int l  = t & 63;
        const int wrB = (w >> 1) * 48;
        const int wcB = (w & 1) * 48;
        const int lrow = l & 15;
        const int lk   = (l >> 4) * 8;

        f32x4 gacc[3][3];
        #pragma unroll
        for (int a = 0; a < 3; ++a)
            #pragma unroll
            for (int cc = 0; cc < 3; ++cc) gacc[a][cc] = (f32x4){0.f, 0.f, 0.f, 0.f};

        #pragma unroll
        for (int k0 = 0; k0 < 64; k0 += 32) {
            #pragma unroll
            for (int a = 0; a < 3; ++a) {
                int arow = wrB + a * 16 + lrow;
                short8 Ah = *(const short8*)&sxh[arow * 72 + k0 + lk];
                short8 Al = *(const short8*)&sxl[arow * 72 + k0 + lk];
                #pragma unroll
                for (int cc = 0; cc < 3; ++cc) {
                    int brow = wcB + cc * 16 + lrow;
                    short8 Bh = *(const short8*)&sxh[brow * 72 + k0 + lk];
                    short8 Bl = *(const short8*)&sxl[brow * 72 + k0 + lk];
                    gacc[a][cc] = __builtin_amdgcn_mfma_f32_16x16x32_bf16(Ah, Bh, gacc[a][cc], 0, 0, 0);
                    gacc[a][cc] = __builtin_amdgcn_mfma_f32_16x16x32_bf16(Ah, Bl, gacc[a][cc], 0, 0, 0);
                    gacc[a][cc] = __builtin_amdgcn_mfma_f32_16x16x32_bf16(Al, Bh, gacc[a][cc], 0, 0, 0);
                    gacc[a][cc] = __builtin_amdgcn_mfma_f32_16x16x32_bf16(Al, Bl, gacc[a][cc], 0, 0, 0);
                }
            }
        }
        __syncthreads();

        #pragma unroll
        for (int a = 0; a < 3; ++a)
            #pragma unroll
            for (int cc = 0; cc < 3; ++cc) {
                int col = wcB + cc * 16 + lrow;
                #pragma unroll
                for (int r = 0; r < 4; ++r) {
                    int row = wrB + a * 16 + (l >> 4) * 4 + r;
                    slin[row * 98 + col] = gacc[a][cc][r];
                }
            }
    }
    __syncthreads();

    float acc[6][6];
    #pragma unroll
    for (int u = 0; u < 6; ++u) {
        int rb = (ti * 6 + u) * 98;
        #pragma unroll
        for (int v = 0; v < 6; v += 2) {
            float2 p = *(const float2*)&slin[rb + tj * 6 + v];
            acc[u][v] = p.x; acc[u][v + 1] = p.y;
        }
    }
    float di[6], dj[6];
    #pragma unroll
    for (int u = 0; u < 6; ++u) { int i = ti * 6 + u; di[u] = slin[i * 98 + i]; }
    #pragma unroll
    for (int v = 0; v < 6; ++v) { int j = tj * 6 + v; dj[v] = slin[j * 98 + j]; }

    #pragma unroll
    for (int u = 0; u < 6; ++u) {
        int i = ti * 6 + u;
        #pragma unroll
        for (int v = 0; v < 6; ++v) {
            int j = tj * 6 + v;
            float lin = acc[u][v];
            float d2 = (di[u] + dj[v] - 2.0f * lin) * inv_ls2;
            d2 = fmaxf(d2, 0.0f);
            float cc = sqrtf(3.0f * d2);
            float nl = (1.0f + cc) * __expf(-cc);
            acc[u][v] = fmaf(sigma2, nl, lin) * inv_nug + ((i == j) ? 1.0f : 0.0f);
        }
    }
    #pragma unroll
    for (int u = 0; u < 6; ++u) {
        size_t row = gbase + (size_t)(ti * 6 + u) * NMAT + tj * 6;
        #pragma unroll
        for (int v = 0; v < 6; v += 2) {
            *(float2*)&outG[row + v] = make_float2(acc[u][v], acc[u][v + 1]);
        }
    }
}

// ====== kernel 2: WAVE-PER-MATRIX cholesky — r16 VERBATIM (PASSED, 683us) ======
// 256 thr, 4 waves, grid NB/4, rolled loops; PHASE_B c2-outer, PHASE_C m-outer.
// FROZEN: four value-identical reschedules (merged-diag x2, 64-thread x2,
// deferred-T11) all NaN'd on hardware; only this skeleton is verified.

#define PHASE_A(D) do {                                                          \
    _Pragma("unroll") for (int c2 = 0; c2 < 6; ++c2) {                           \
        float s = D[c2][c2];                                                     \
        _Pragma("unroll") for (int m = 0; m < 6; ++m) if (m < c2) s -= D[c2][m] * D[c2][m]; \
        float l = sqrtf(s);                                                      \
        D[c2][c2] = l;                                                           \
        float rinv = 1.0f / l;                                                   \
        rinvp[c2] = rinv;                                                        \
        _Pragma("unroll") for (int rr = 0; rr < 6; ++rr) if (rr > c2) {          \
            float s2 = D[rr][c2];                                                \
            _Pragma("unroll") for (int m = 0; m < 6; ++m) if (m < c2) s2 -= D[rr][m] * D[c2][m]; \
            D[rr][c2] = s2 * rinv;                                               \
        }                                                                        \
    }                                                                            \
    _Pragma("unroll") for (int u = 0; u < 6; ++u) {                              \
        *(float4*)&L6p[u * 8]     = make_float4(D[u][0], D[u][1], D[u][2], D[u][3]); \
        *(float2*)&L6p[u * 8 + 4] = make_float2(D[u][4], D[u][5]);               \
    }                                                                            \
} while (0)

#define PHASE_B(D, TIEFF) do {                                                   \
    _Pragma("unroll") for (int c2 = 0; c2 < 6; ++c2) {                           \
        float4 p = *(const float4*)&L6p[c2 * 8];                                 \
        float2 q = *(const float2*)&L6p[c2 * 8 + 4];                             \
        float a0 = p.x, a1 = p.y, a2 = p.z, a3 = p.w, a4 = q.x;                  \
        (void)q;                                                                 \
        float rinv = rinvp[c2];                                                  \
        _Pragma("unroll") for (int u = 0; u < 6; ++u) {                          \
            float s = D[u][c2];                                                  \
            if (c2 > 0) s -= D[u][0] * a0;                                       \
            if (c2 > 1) s -= D[u][1] * a1;                                       \
            if (c2 > 2) s -= D[u][2] * a2;                                       \
            if (c2 > 3) s -= D[u][3] * a3;                                       \
            if (c2 > 4) s -= D[u][4] * a4;                                       \
            D[u][c2] = s * rinv;                                                 \
        }                                                                        \
    }                                                                            \
    _Pragma("unroll") for (int u = 0; u < 6; ++u) {                              \
        int prow = (TIEFF) * 6 + u;                                              \
        *(float4*)&panel[prow * 12]     = make_float4(D[u][0], D[u][1], D[u][2], D[u][3]); \
        *(float2*)&panel[prow * 12 + 4] = make_float2(D[u][4], D[u][5]);         \
    }                                                                            \
} while (0)

#define PHASE_C(D, TIEFF, TJEFF) do {                                            \
    _Pragma("unroll") for (int m = 0; m < 6; ++m) {                              \
        float pum[6], pvm[6];                                                    \
        _Pragma("unroll") for (int u = 0; u < 6; ++u)                            \
            pum[u] = panel[((TIEFF) * 6 + u) * 12 + m];                          \
        _Pragma("unroll") for (int v = 0; v < 6; ++v)                            \
            pvm[v] = panel[((TJEFF) * 6 + v) * 12 + m];                          \
        _Pragma("unroll") for (int u = 0; u < 6; ++u)                            \
            _Pragma("unroll") for (int v = 0; v < 6; ++v)                        \
                D[u][v] = fmaf(-pum[u], pvm[v], D[u][v]);                        \
    }                                                                            \
} while (0)

#define STORE_TILE(D, TIEFF, TJEFF) do {                                         \
    _Pragma("unroll") for (int u = 0; u < 6; ++u) {                              \
        const int i2 = (TIEFF) * 6 + u;                                          \
        size_t rowp = gbase + (size_t)i2 * NMAT + (TJEFF) * 6;                   \
        _Pragma("unroll") for (int v = 0; v < 6; v += 2) {                       \
            int j0 = (TJEFF) * 6 + v;                                            \
            float a0 = D[u][v], a1 = D[u][v + 1];                                \
            if ((TIEFF) < (TJEFF)) { a0 = 0.0f; a1 = 0.0f; }                     \
            else if ((TIEFF) == (TJEFF)) {                                       \
                if (j0 > i2)     a0 = 0.0f;                                      \
                if (j0 + 1 > i2) a1 = 0.0f;                                      \
            }                                                                    \
            *(float2*)&outL[rowp + v] = make_float2(a0, a1);                     \
        }                                                                        \
    }                                                                            \
} while (0)

#define LOAD_TILE(D, TIEFF, TJEFF) do {                                          \
    _Pragma("unroll") for (int u = 0; u < 6; ++u) {                              \
        size_t rowp = gbase + (size_t)((TIEFF) * 6 + u) * NMAT + (TJEFF) * 6;    \
        float2 p0 = *(const float2*)&outG[rowp + 0];                             \
        float2 p1 = *(const float2*)&outG[rowp + 2];                             \
        float2 p2 = *(const float2*)&outG[rowp + 4];                             \
        D[u][0] = p0.x; D[u][1] = p0.y; D[u][2] = p1.x;                          \
        D[u][3] = p1.y; D[u][4] = p2.x; D[u][5] = p2.y;                          \
    }                                                                            \
} while (0)

__launch_bounds__(256)
__global__ void chol_kernel(const float* __restrict__ outG,
                            float* __restrict__ outL)
{
    const int w    = threadIdx.x >> 6;   // wave id 0..3 -> matrix
    const int lane = threadIdx.x & 63;
    const int wi   = lane >> 3;          // 0..7 row-tile
    const int wj   = lane & 7;           // 0..7 col-tile
    const int b    = blockIdx.x * 4 + w;
    const size_t gbase = (size_t)b * (NMAT * NMAT);

    __shared__ float spanel_all[4][96][12];
    __shared__ float sL6_all[4][6][8];
    __shared__ float srinv_all[4][8];
    float* panel = &spanel_all[w][0][0];
    float* L6p   = &sL6_all[w][0][0];
    float* rinvp = &srinv_all[w][0];

    float acc00[6][6], acc10[6][6], acc11[6][6];

    LOAD_TILE(acc00, wi,     wj);
    LOAD_TILE(acc10, 8 + wi, wj);
    LOAD_TILE(acc11, 8 + wi, 8 + wj);

    #pragma unroll 1
    for (int jb = 0; jb < 8; ++jb) {
        const int J = jb;
        if (wi == J && wj == J) PHASE_A(acc00);
        if (wj == J && wi > J) PHASE_B(acc00, wi);
        if (wj == J)           PHASE_B(acc10, 8 + wi);
        if (wj > J && wi >= wj) PHASE_C(acc00, wi, wj);
        if (wj > J)             PHASE_C(acc10, 8 + wi, wj);
        if (wi >= wj)           PHASE_C(acc11, 8 + wi, 8 + wj);
    }
    #pragma unroll 1
    for (int jb = 8; jb < 16; ++jb) {
        const int J = jb - 8;
        if (wi == J && wj == J) PHASE_A(acc11);
        if (wj == J && wi > J) PHASE_B(acc11, 8 + wi);
        if (wj > J && wi >= wj) PHASE_C(acc11, 8 + wi, 8 + wj);
    }

    STORE_TILE(acc00, wi,     wj);
    STORE_TILE(acc10, 8 + wi, wj);
    STORE_TILE(acc11, 8 + wi, 8 + wj);
    #pragma unroll
    for (int u = 0; u < 6; ++u) {
        size_t rowp = gbase + (size_t)(wi * 6 + u) * NMAT + (8 + wj) * 6;
        *(float2*)&outL[rowp + 0] = make_float2(0.0f, 0.0f);
        *(float2*)&outL[rowp + 2] = make_float2(0.0f, 0.0f);
        *(float2*)&outL[rowp + 4] = make_float2(0.0f, 0.0f);
    }
}

extern "C" void kernel_launch(void* const* d_in, const int* in_sizes, int n_in,
                              void* d_out, int out_size, void* d_ws, size_t ws_size,
                              hipStream_t stream) {
    const float* kp     = (const float*)d_in[0];
    const float* aug    = (const float*)d_in[1];
    const float* scales = (const float*)d_in[2];
    const float* nug    = (const float*)d_in[3];
    float* out = (float*)d_out;
    unsigned* ws = (unsigned*)d_ws;

    float* outG = out;
    float* outL = out + (size_t)NB * NMAT * NMAT;

    hipMemsetAsync(ws, 0xFF, 4, stream);
    minnz_kernel<<<(NB + 255) / 256, 256, 0, stream>>>(scales, ws);
    gram_kernel<<<NB, 256, 0, stream>>>(kp, aug, scales, nug, ws, out);
    chol_kernel<<<NB / 4, 256, 0, stream>>>(outG, outL);
}

// Round 19
// 609.679 us; speedup vs baseline: 4.4010x; 1.3524x over previous
//
#include <hip/hip_runtime.h>
#include <math.h>

#define N_LOCS 16384
#define START 4096
#define NB 12288
#define NMAT 96
#define KDIM 60

typedef __attribute__((ext_vector_type(8))) short short8;
typedef __attribute__((ext_vector_type(4))) float f32x4;

#define SBAR __builtin_amdgcn_sched_barrier(0)

__global__ void minnz_kernel(const float* __restrict__ scales, unsigned* __restrict__ ws) {
    int idx = blockIdx.x * 256 + threadIdx.x;
    if (idx < NB) {
        float v = scales[START + idx];
        if (v != 0.0f) atomicMin(ws, __float_as_uint(v));
    }
}

__device__ __forceinline__ unsigned short f32_to_bf16_rne(float f, float* back) {
    unsigned u = __float_as_uint(f);
    unsigned r = (u + 0x7fffu + ((u >> 16) & 1u)) >> 16;
    *back = __uint_as_float(r << 16);
    return (unsigned short)r;
}

// ============ kernel 1: gram + transform + write g (r18-verified, unchanged) ============
__launch_bounds__(256)
__global__ void gram_kernel(const float* __restrict__ kp,
                            const float* __restrict__ aug,
                            const float* __restrict__ scales,
                            const float* __restrict__ nug,
                            const unsigned* __restrict__ ws,
                            float* __restrict__ out)
{
    const int b = blockIdx.x;
    const int t = threadIdx.x;
    const int ti = t >> 4, tj = t & 15;

    float* outG = out;                                   // [NB][96][96]
    float* outN = out + 2 * (size_t)NB * NMAT * NMAT;    // [NB]

    if (t == 0) outN[b] = nug[b];

    const size_t gbase = (size_t)b * (NMAT * NMAT);

    if (b == 0) {
        #pragma unroll
        for (int u = 0; u < 6; ++u) {
            int i = ti * 6 + u;
            #pragma unroll
            for (int v = 0; v < 6; ++v) {
                int j = tj * 6 + v;
                outG[gbase + (size_t)i * NMAT + j] = (i == j) ? 1.0f : 0.0f;
            }
        }
        return;
    }

    __shared__ char smem[37632];
    unsigned short* sxh  = (unsigned short*)smem;
    unsigned short* sxl  = (unsigned short*)(smem + 13824);
    float*          slin = (float*)smem;

    const float kp1 = kp[1], kp3 = kp[3], kp5 = kp[5], kp7 = kp[7];
    const float kp8 = kp[8], kp9 = kp[9], kp11 = kp[11];
    float sc = scales[START + b];
    if (sc == 0.0f) sc = __uint_as_float(ws[0]) * 0.5f;
    const float sigma   = __expf(kp1 + kp3 * __logf(sc));
    const float sigma2  = sigma * sigma;
    const float inv_ls2 = 1.0f / (3.0f * __expf(2.0f * kp11));
    const float inv_nug = 1.0f / nug[b];

    const int c = t & 63;
    float myscale = 0.0f;
    if (c < KDIM) {
        float kf = (c < 30) ? (float)(c + 1) : (float)(c - 29);
        float th = (c < 30) ? kp5 : kp8;
        float de = (c < 30) ? kp7 : kp9;
        myscale = __expf(th - 0.5f * __expf(de) * kf);
    }

    {
        const int rgrp = t >> 6;
        const size_t rowstride = (size_t)N_LOCS * 61;
        const size_t base = (size_t)(START + b) * 61 + 1 + c;
        #pragma unroll
        for (int half = 0; half < 2; ++half) {
            float vb[12];
            #pragma unroll
            for (int it = 0; it < 12; ++it) {
                int i = (half * 12 + it) * 4 + rgrp;
                vb[it] = (c < KDIM) ? aug[base + (size_t)i * rowstride] : 0.0f;
            }
            #pragma unroll
            for (int it = 0; it < 12; ++it) {
                int i = (half * 12 + it) * 4 + rgrp;
                float v = vb[it];
                v = (v != v) ? 0.0f : v;
                v *= myscale;
                float fh;
                unsigned short hb = f32_to_bf16_rne(v, &fh);
                float dummy;
                unsigned short lb = f32_to_bf16_rne(v - fh, &dummy);
                sxh[i * 72 + c] = hb;
                sxl[i * 72 + c] = lb;
            }
        }
    }
    __syncthreads();

    {
        const int w  = t >> 6;
        const int l  = t & 63;
        const int wrB = (w >> 1) * 48;
        const int wcB = (w & 1) * 48;
        const int lrow = l & 15;
        const int lk   = (l >> 4) * 8;

        f32x4 gacc[3][3];
        #pragma unroll
        for (int a = 0; a < 3; ++a)
            #pragma unroll
            for (int cc = 0; cc < 3; ++cc) gacc[a][cc] = (f32x4){0.f, 0.f, 0.f, 0.f};

        #pragma unroll
        for (int k0 = 0; k0 < 64; k0 += 32) {
            #pragma unroll
            for (int a = 0; a < 3; ++a) {
                int arow = wrB + a * 16 + lrow;
                short8 Ah = *(const short8*)&sxh[arow * 72 + k0 + lk];
                short8 Al = *(const short8*)&sxl[arow * 72 + k0 + lk];
                #pragma unroll
                for (int cc = 0; cc < 3; ++cc) {
                    int brow = wcB + cc * 16 + lrow;
                    short8 Bh = *(const short8*)&sxh[brow * 72 + k0 + lk];
                    short8 Bl = *(const short8*)&sxl[brow * 72 + k0 + lk];
                    gacc[a][cc] = __builtin_amdgcn_mfma_f32_16x16x32_bf16(Ah, Bh, gacc[a][cc], 0, 0, 0);
                    gacc[a][cc] = __builtin_amdgcn_mfma_f32_16x16x32_bf16(Ah, Bl, gacc[a][cc], 0, 0, 0);
                    gacc[a][cc] = __builtin_amdgcn_mfma_f32_16x16x32_bf16(Al, Bh, gacc[a][cc], 0, 0, 0);
                    gacc[a][cc] = __builtin_amdgcn_mfma_f32_16x16x32_bf16(Al, Bl, gacc[a][cc], 0, 0, 0);
                }
            }
        }
        __syncthreads();

        #pragma unroll
        for (int a = 0; a < 3; ++a)
            #pragma unroll
            for (int cc = 0; cc < 3; ++cc) {
                int col = wcB + cc * 16 + lrow;
                #pragma unroll
                for (int r = 0; r < 4; ++r) {
                    int row = wrB + a * 16 + (l >> 4) * 4 + r;
                    slin[row * 98 + col] = gacc[a][cc][r];
                }
            }
    }
    __syncthreads();

    float acc[6][6];
    #pragma unroll
    for (int u = 0; u < 6; ++u) {
        int rb = (ti * 6 + u) * 98;
        #pragma unroll
        for (int v = 0; v < 6; v += 2) {
            float2 p = *(const float2*)&slin[rb + tj * 6 + v];
            acc[u][v] = p.x; acc[u][v + 1] = p.y;
        }
    }
    float di[6], dj[6];
    #pragma unroll
    for (int u = 0; u < 6; ++u) { int i = ti * 6 + u; di[u] = slin[i * 98 + i]; }
    #pragma unroll
    for (int v = 0; v < 6; ++v) { int j = tj * 6 + v; dj[v] = slin[j * 98 + j]; }

    #pragma unroll
    for (int u = 0; u < 6; ++u) {
        int i = ti * 6 + u;
        #pragma unroll
        for (int v = 0; v < 6; ++v) {
            int j = tj * 6 + v;
            float lin = acc[u][v];
            float d2 = (di[u] + dj[v] - 2.0f * lin) * inv_ls2;
            d2 = fmaxf(d2, 0.0f);
            float cc = sqrtf(3.0f * d2);
            float nl = (1.0f + cc) * __expf(-cc);
            acc[u][v] = fmaf(sigma2, nl, lin) * inv_nug + ((i == j) ? 1.0f : 0.0f);
        }
    }
    #pragma unroll
    for (int u = 0; u < 6; ++u) {
        size_t row = gbase + (size_t)(ti * 6 + u) * NMAT + tj * 6;
        #pragma unroll
        for (int v = 0; v < 6; v += 2) {
            *(float2*)&outG[row + v] = make_float2(acc[u][v], acc[u][v + 1]);
        }
    }
}

// ====== kernel 2: WAVE-PER-MATRIX cholesky — r16 skeleton + DEFERRED T11 ======
// Fortifications vs the failed r17: (1) sched_barrier(0) at every phase
// boundary (semantic no-op; blocks compiler code motion across LDS deps —
// guide rule #18 hazard); (2) Pbuf persistence = register-sourced scalar
// stores purely ADDED to the r16-passing first loop (no existing access
// changed); deferred reads scalar. Update order jb-asc, m-asc => bitwise
// identical values to r16.

#define PHASE_A(D) do {                                                          \
    _Pragma("unroll") for (int c2 = 0; c2 < 6; ++c2) {                           \
        float s = D[c2][c2];                                                     \
        _Pragma("unroll") for (int m = 0; m < 6; ++m) if (m < c2) s -= D[c2][m] * D[c2][m]; \
        float l = sqrtf(s);                                                      \
        D[c2][c2] = l;                                                           \
        float rinv = 1.0f / l;                                                   \
        rinvp[c2] = rinv;                                                        \
        _Pragma("unroll") for (int rr = 0; rr < 6; ++rr) if (rr > c2) {          \
            float s2 = D[rr][c2];                                                \
            _Pragma("unroll") for (int m = 0; m < 6; ++m) if (m < c2) s2 -= D[rr][m] * D[c2][m]; \
            D[rr][c2] = s2 * rinv;                                               \
        }                                                                        \
    }                                                                            \
    _Pragma("unroll") for (int u = 0; u < 6; ++u) {                              \
        *(float4*)&L6p[u * 8]     = make_float4(D[u][0], D[u][1], D[u][2], D[u][3]); \
        *(float2*)&L6p[u * 8 + 4] = make_float2(D[u][4], D[u][5]);               \
    }                                                                            \
} while (0)

#define PHASE_B(D, TIEFF) do {                                                   \
    _Pragma("unroll") for (int c2 = 0; c2 < 6; ++c2) {                           \
        float4 p = *(const float4*)&L6p[c2 * 8];                                 \
        float2 q = *(const float2*)&L6p[c2 * 8 + 4];                             \
        float a0 = p.x, a1 = p.y, a2 = p.z, a3 = p.w, a4 = q.x;                  \
        (void)q;                                                                 \
        float rinv = rinvp[c2];                                                  \
        _Pragma("unroll") for (int u = 0; u < 6; ++u) {                          \
            float s = D[u][c2];                                                  \
            if (c2 > 0) s -= D[u][0] * a0;                                       \
            if (c2 > 1) s -= D[u][1] * a1;                                       \
            if (c2 > 2) s -= D[u][2] * a2;                                       \
            if (c2 > 3) s -= D[u][3] * a3;                                       \
            if (c2 > 4) s -= D[u][4] * a4;                                       \
            D[u][c2] = s * rinv;                                                 \
        }                                                                        \
    }                                                                            \
    _Pragma("unroll") for (int u = 0; u < 6; ++u) {                              \
        int prow = (TIEFF) * 6 + u;                                              \
        *(float4*)&panel[prow * 12]     = make_float4(D[u][0], D[u][1], D[u][2], D[u][3]); \
        *(float2*)&panel[prow * 12 + 4] = make_float2(D[u][4], D[u][5]);         \
    }                                                                            \
} while (0)

// register-sourced scalar persistence of the just-solved acc10 panel rows
#define PERSIST10(D, CB) do {                                                    \
    _Pragma("unroll") for (int u = 0; u < 6; ++u)                                \
        _Pragma("unroll") for (int x = 0; x < 6; ++x)                            \
            Pbuf[(wi * 6 + u) * 49 + (CB) + x] = D[u][x];                        \
} while (0)

#define PHASE_C(D, TIEFF, TJEFF) do {                                            \
    _Pragma("unroll") for (int m = 0; m < 6; ++m) {                              \
        float pum[6], pvm[6];                                                    \
        _Pragma("unroll") for (int u = 0; u < 6; ++u)                            \
            pum[u] = panel[((TIEFF) * 6 + u) * 12 + m];                          \
        _Pragma("unroll") for (int v = 0; v < 6; ++v)                            \
            pvm[v] = panel[((TJEFF) * 6 + v) * 12 + m];                          \
        _Pragma("unroll") for (int u = 0; u < 6; ++u)                            \
            _Pragma("unroll") for (int v = 0; v < 6; ++v)                        \
                D[u][v] = fmaf(-pum[u], pvm[v], D[u][v]);                        \
    }                                                                            \
} while (0)

// deferred rank-6 from Pbuf (scalar reads), m-outer as PHASE_C
#define PHASE_C_P(D, RU, RV, CB) do {                                            \
    _Pragma("unroll") for (int m = 0; m < 6; ++m) {                              \
        float pum[6], pvm[6];                                                    \
        _Pragma("unroll") for (int u = 0; u < 6; ++u)                            \
            pum[u] = Pbuf[((RU) * 6 + u) * 49 + (CB) + m];                       \
        _Pragma("unroll") for (int v = 0; v < 6; ++v)                            \
            pvm[v] = Pbuf[((RV) * 6 + v) * 49 + (CB) + m];                       \
        _Pragma("unroll") for (int u = 0; u < 6; ++u)                            \
            _Pragma("unroll") for (int v = 0; v < 6; ++v)                        \
                D[u][v] = fmaf(-pum[u], pvm[v], D[u][v]);                        \
    }                                                                            \
} while (0)

#define STORE_TILE(D, TIEFF, TJEFF) do {                                         \
    _Pragma("unroll") for (int u = 0; u < 6; ++u) {                              \
        const int i2 = (TIEFF) * 6 + u;                                          \
        size_t rowp = gbase + (size_t)i2 * NMAT + (TJEFF) * 6;                   \
        _Pragma("unroll") for (int v = 0; v < 6; v += 2) {                       \
            int j0 = (TJEFF) * 6 + v;                                            \
            float a0 = D[u][v], a1 = D[u][v + 1];                                \
            if ((TIEFF) < (TJEFF)) { a0 = 0.0f; a1 = 0.0f; }                     \
            else if ((TIEFF) == (TJEFF)) {                                       \
                if (j0 > i2)     a0 = 0.0f;                                      \
                if (j0 + 1 > i2) a1 = 0.0f;                                      \
            }                                                                    \
            *(float2*)&outL[rowp + v] = make_float2(a0, a1);                     \
        }                                                                        \
    }                                                                            \
} while (0)

#define LOAD_TILE(D, TIEFF, TJEFF) do {                                          \
    _Pragma("unroll") for (int u = 0; u < 6; ++u) {                              \
        size_t rowp = gbase + (size_t)((TIEFF) * 6 + u) * NMAT + (TJEFF) * 6;    \
        float2 p0 = *(const float2*)&outG[rowp + 0];                             \
        float2 p1 = *(const float2*)&outG[rowp + 2];                             \
        float2 p2 = *(const float2*)&outG[rowp + 4];                             \
        D[u][0] = p0.x; D[u][1] = p0.y; D[u][2] = p1.x;                          \
        D[u][3] = p1.y; D[u][4] = p2.x; D[u][5] = p2.y;                          \
    }                                                                            \
} while (0)

__launch_bounds__(256)
__global__ void chol_kernel(const float* __restrict__ outG,
                            float* __restrict__ outL)
{
    const int w    = threadIdx.x >> 6;   // wave id 0..3 -> matrix
    const int lane = threadIdx.x & 63;
    const int wi   = lane >> 3;          // 0..7 row-tile
    const int wj   = lane & 7;           // 0..7 col-tile
    const int b    = blockIdx.x * 4 + w;
    const size_t gbase = (size_t)b * (NMAT * NMAT);

    __shared__ float spanel_all[4][96][12];
    __shared__ float sPbuf_all[4][48][49];   // persistent T10/T11 panels
    __shared__ float sL6_all[4][6][8];
    __shared__ float srinv_all[4][8];
    float* panel = &spanel_all[w][0][0];
    float* Pbuf  = &sPbuf_all[w][0][0];
    float* L6p   = &sL6_all[w][0][0];
    float* rinvp = &srinv_all[w][0];

    float acc00[6][6], acc10[6][6];

    LOAD_TILE(acc00, wi,     wj);
    LOAD_TILE(acc10, 8 + wi, wj);

    // ---- first half: r16's first loop + additive Pbuf persistence ----
    #pragma unroll 1
    for (int jb = 0; jb < 8; ++jb) {
        const int J = jb;
        if (wi == J && wj == J) PHASE_A(acc00);
        SBAR;
        if (wj == J && wi > J) PHASE_B(acc00, wi);
        if (wj == J)           { PHASE_B(acc10, 8 + wi); PERSIST10(acc10, J * 6); }
        SBAR;
        if (wj > J && wi >= wj) PHASE_C(acc00, wi, wj);
        if (wj > J)             PHASE_C(acc10, 8 + wi, wj);
        SBAR;
    }

    // ---- acc00/acc10 final: store, freeing registers ----
    STORE_TILE(acc00, wi,     wj);
    STORE_TILE(acc10, 8 + wi, wj);
    #pragma unroll
    for (int u = 0; u < 6; ++u) {
        size_t rowp = gbase + (size_t)(wi * 6 + u) * NMAT + (8 + wj) * 6;
        *(float2*)&outL[rowp + 0] = make_float2(0.0f, 0.0f);
        *(float2*)&outL[rowp + 2] = make_float2(0.0f, 0.0f);
        *(float2*)&outL[rowp + 4] = make_float2(0.0f, 0.0f);
    }
    SBAR;

    // ---- load g11; apply the 8 deferred rank-6 updates (jb asc, m asc) ----
    float acc11[6][6];
    LOAD_TILE(acc11, 8 + wi, 8 + wj);
    #pragma unroll 1
    for (int jb2 = 0; jb2 < 8; ++jb2) {
        if (wi >= wj) PHASE_C_P(acc11, wi, wj, jb2 * 6);
        SBAR;
    }

    // ---- second half: verbatim r16 second loop (panel-based) ----
    #pragma unroll 1
    for (int jb = 8; jb < 16; ++jb) {
        const int J = jb - 8;
        if (wi == J && wj == J) PHASE_A(acc11);
        SBAR;
        if (wj == J && wi > J) PHASE_B(acc11, 8 + wi);
        SBAR;
        if (wj > J && wi >= wj) PHASE_C(acc11, 8 + wi, 8 + wj);
        SBAR;
    }

    STORE_TILE(acc11, 8 + wi, 8 + wj);
}

extern "C" void kernel_launch(void* const* d_in, const int* in_sizes, int n_in,
                              void* d_out, int out_size, void* d_ws, size_t ws_size,
                              hipStream_t stream) {
    const float* kp     = (const float*)d_in[0];
    const float* aug    = (const float*)d_in[1];
    const float* scales = (const float*)d_in[2];
    const float* nug    = (const float*)d_in[3];
    float* out = (float*)d_out;
    unsigned* ws = (unsigned*)d_ws;

    float* outG = out;
    float* outL = out + (size_t)NB * NMAT * NMAT;

    hipMemsetAsync(ws, 0xFF, 4, stream);
    minnz_kernel<<<(NB + 255) / 256, 256, 0, stream>>>(scales, ws);
    gram_kernel<<<NB, 256, 0, stream>>>(kp, aug, scales, nug, ws, out);
    chol_kernel<<<NB / 4, 256, 0, stream>>>(outG, outL);
}

// Round 20
// 607.786 us; speedup vs baseline: 4.4147x; 1.0031x over previous
//
#include <hip/hip_runtime.h>
#include <math.h>

#define N_LOCS 16384
#define START 4096
#define NB 12288
#define NMAT 96
#define KDIM 60

typedef __attribute__((ext_vector_type(8))) short short8;
typedef __attribute__((ext_vector_type(4))) float f32x4;

#define SBAR __builtin_amdgcn_sched_barrier(0)

__global__ void minnz_kernel(const float* __restrict__ scales, unsigned* __restrict__ ws) {
    int idx = blockIdx.x * 256 + threadIdx.x;
    if (idx < NB) {
        float v = scales[START + idx];
        if (v != 0.0f) atomicMin(ws, __float_as_uint(v));
    }
}

__device__ __forceinline__ unsigned short f32_to_bf16_rne(float f, float* back) {
    unsigned u = __float_as_uint(f);
    unsigned r = (u + 0x7fffu + ((u >> 16) & 1u)) >> 16;
    *back = __uint_as_float(r << 16);
    return (unsigned short)r;
}

// ============ kernel 1: gram + transform + write g (r18-verified, unchanged) ============
__launch_bounds__(256)
__global__ void gram_kernel(const float* __restrict__ kp,
                            const float* __restrict__ aug,
                            const float* __restrict__ scales,
                            const float* __restrict__ nug,
                            const unsigned* __restrict__ ws,
                            float* __restrict__ out)
{
    const int b = blockIdx.x;
    const int t = threadIdx.x;
    const int ti = t >> 4, tj = t & 15;

    float* outG = out;                                   // [NB][96][96]
    float* outN = out + 2 * (size_t)NB * NMAT * NMAT;    // [NB]

    if (t == 0) outN[b] = nug[b];

    const size_t gbase = (size_t)b * (NMAT * NMAT);

    if (b == 0) {
        #pragma unroll
        for (int u = 0; u < 6; ++u) {
            int i = ti * 6 + u;
            #pragma unroll
            for (int v = 0; v < 6; ++v) {
                int j = tj * 6 + v;
                outG[gbase + (size_t)i * NMAT + j] = (i == j) ? 1.0f : 0.0f;
            }
        }
        return;
    }

    __shared__ char smem[37632];
    unsigned short* sxh  = (unsigned short*)smem;
    unsigned short* sxl  = (unsigned short*)(smem + 13824);
    float*          slin = (float*)smem;

    const float kp1 = kp[1], kp3 = kp[3], kp5 = kp[5], kp7 = kp[7];
    const float kp8 = kp[8], kp9 = kp[9], kp11 = kp[11];
    float sc = scales[START + b];
    if (sc == 0.0f) sc = __uint_as_float(ws[0]) * 0.5f;
    const float sigma   = __expf(kp1 + kp3 * __logf(sc));
    const float sigma2  = sigma * sigma;
    const float inv_ls2 = 1.0f / (3.0f * __expf(2.0f * kp11));
    const float inv_nug = 1.0f / nug[b];

    const int c = t & 63;
    float myscale = 0.0f;
    if (c < KDIM) {
        float kf = (c < 30) ? (float)(c + 1) : (float)(c - 29);
        float th = (c < 30) ? kp5 : kp8;
        float de = (c < 30) ? kp7 : kp9;
        myscale = __expf(th - 0.5f * __expf(de) * kf);
    }

    {
        const int rgrp = t >> 6;
        const size_t rowstride = (size_t)N_LOCS * 61;
        const size_t base = (size_t)(START + b) * 61 + 1 + c;
        #pragma unroll
        for (int half = 0; half < 2; ++half) {
            float vb[12];
            #pragma unroll
            for (int it = 0; it < 12; ++it) {
                int i = (half * 12 + it) * 4 + rgrp;
                vb[it] = (c < KDIM) ? aug[base + (size_t)i * rowstride] : 0.0f;
            }
            #pragma unroll
            for (int it = 0; it < 12; ++it) {
                int i = (half * 12 + it) * 4 + rgrp;
                float v = vb[it];
                v = (v != v) ? 0.0f : v;
                v *= myscale;
                float fh;
                unsigned short hb = f32_to_bf16_rne(v, &fh);
                float dummy;
                unsigned short lb = f32_to_bf16_rne(v - fh, &dummy);
                sxh[i * 72 + c] = hb;
                sxl[i * 72 + c] = lb;
            }
        }
    }
    __syncthreads();

    {
        const int w  = t >> 6;
        const int l  = t & 63;
        const int wrB = (w >> 1) * 48;
        const int wcB = (w & 1) * 48;
        const int lrow = l & 15;
        const int lk   = (l >> 4) * 8;

        f32x4 gacc[3][3];
        #pragma unroll
        for (int a = 0; a < 3; ++a)
            #pragma unroll
            for (int cc = 0; cc < 3; ++cc) gacc[a][cc] = (f32x4){0.f, 0.f, 0.f, 0.f};

        #pragma unroll
        for (int k0 = 0; k0 < 64; k0 += 32) {
            #pragma unroll
            for (int a = 0; a < 3; ++a) {
                int arow = wrB + a * 16 + lrow;
                short8 Ah = *(const short8*)&sxh[arow * 72 + k0 + lk];
                short8 Al = *(const short8*)&sxl[arow * 72 + k0 + lk];
                #pragma unroll
                for (int cc = 0; cc < 3; ++cc) {
                    int brow = wcB + cc * 16 + lrow;
                    short8 Bh = *(const short8*)&sxh[brow * 72 + k0 + lk];
                    short8 Bl = *(const short8*)&sxl[brow * 72 + k0 + lk];
                    gacc[a][cc] = __builtin_amdgcn_mfma_f32_16x16x32_bf16(Ah, Bh, gacc[a][cc], 0, 0, 0);
                    gacc[a][cc] = __builtin_amdgcn_mfma_f32_16x16x32_bf16(Ah, Bl, gacc[a][cc], 0, 0, 0);
                    gacc[a][cc] = __builtin_amdgcn_mfma_f32_16x16x32_bf16(Al, Bh, gacc[a][cc], 0, 0, 0);
                    gacc[a][cc] = __builtin_amdgcn_mfma_f32_16x16x32_bf16(Al, Bl, gacc[a][cc], 0, 0, 0);
                }
            }
        }
        __syncthreads();

        #pragma unroll
        for (int a = 0; a < 3; ++a)
            #pragma unroll
            for (int cc = 0; cc < 3; ++cc) {
                int col = wcB + cc * 16 + lrow;
                #pragma unroll
                for (int r = 0; r < 4; ++r) {
                    int row = wrB + a * 16 + (l >> 4) * 4 + r;
                    slin[row * 98 + col] = gacc[a][cc][r];
                }
            }
    }
    __syncthreads();

    float acc[6][6];
    #pragma unroll
    for (int u = 0; u < 6; ++u) {
        int rb = (ti * 6 + u) * 98;
        #pragma unroll
        for (int v = 0; v < 6; v += 2) {
            float2 p = *(const float2*)&slin[rb + tj * 6 + v];
            acc[u][v] = p.x; acc[u][v + 1] = p.y;
        }
    }
    float di[6], dj[6];
    #pragma unroll
    for (int u = 0; u < 6; ++u) { int i = ti * 6 + u; di[u] = slin[i * 98 + i]; }
    #pragma unroll
    for (int v = 0; v < 6; ++v) { int j = tj * 6 + v; dj[v] = slin[j * 98 + j]; }

    #pragma unroll
    for (int u = 0; u < 6; ++u) {
        int i = ti * 6 + u;
        #pragma unroll
        for (int v = 0; v < 6; ++v) {
            int j = tj * 6 + v;
            float lin = acc[u][v];
            float d2 = (di[u] + dj[v] - 2.0f * lin) * inv_ls2;
            d2 = fmaxf(d2, 0.0f);
            float cc = sqrtf(3.0f * d2);
            float nl = (1.0f + cc) * __expf(-cc);
            acc[u][v] = fmaf(sigma2, nl, lin) * inv_nug + ((i == j) ? 1.0f : 0.0f);
        }
    }
    #pragma unroll
    for (int u = 0; u < 6; ++u) {
        size_t row = gbase + (size_t)(ti * 6 + u) * NMAT + tj * 6;
        #pragma unroll
        for (int v = 0; v < 6; v += 2) {
            *(float2*)&outG[row + v] = make_float2(acc[u][v], acc[u][v + 1]);
        }
    }
}

// ====== kernel 2: WAVE-PER-MATRIX cholesky — r19-verified skeleton, LDS-slimmed ======
// Deltas vs r19 (PASSED, fortified pattern retained — SBAR at phase bounds):
//   1. B10 no longer writes the transient panel (rows 48-95 deleted); C10 reads
//      its pu rows from Pbuf instead (PHASE_C_MIX) — identical values written by
//      PERSIST10 in the same phase.
//   2. Second half's panel rows shifted -48 (pure LDS address relocation).
// spanel: [96][12] -> [48][12]. LDS/block 57KB -> 46.6KB => 3 blocks/CU.

#define PHASE_A(D) do {                                                          \
    _Pragma("unroll") for (int c2 = 0; c2 < 6; ++c2) {                           \
        float s = D[c2][c2];                                                     \
        _Pragma("unroll") for (int m = 0; m < 6; ++m) if (m < c2) s -= D[c2][m] * D[c2][m]; \
        float l = sqrtf(s);                                                      \
        D[c2][c2] = l;                                                           \
        float rinv = 1.0f / l;                                                   \
        rinvp[c2] = rinv;                                                        \
        _Pragma("unroll") for (int rr = 0; rr < 6; ++rr) if (rr > c2) {          \
            float s2 = D[rr][c2];                                                \
            _Pragma("unroll") for (int m = 0; m < 6; ++m) if (m < c2) s2 -= D[rr][m] * D[c2][m]; \
            D[rr][c2] = s2 * rinv;                                               \
        }                                                                        \
    }                                                                            \
    _Pragma("unroll") for (int u = 0; u < 6; ++u) {                              \
        *(float4*)&L6p[u * 8]     = make_float4(D[u][0], D[u][1], D[u][2], D[u][3]); \
        *(float2*)&L6p[u * 8 + 4] = make_float2(D[u][4], D[u][5]);               \
    }                                                                            \
} while (0)

// c2-outer triangular solve (r16/r19-passing form), no publish
#define PHASE_B_SOLVE(D) do {                                                    \
    _Pragma("unroll") for (int c2 = 0; c2 < 6; ++c2) {                           \
        float4 p = *(const float4*)&L6p[c2 * 8];                                 \
        float2 q = *(const float2*)&L6p[c2 * 8 + 4];                             \
        float a0 = p.x, a1 = p.y, a2 = p.z, a3 = p.w, a4 = q.x;                  \
        (void)q;                                                                 \
        float rinv = rinvp[c2];                                                  \
        _Pragma("unroll") for (int u = 0; u < 6; ++u) {                          \
            float s = D[u][c2];                                                  \
            if (c2 > 0) s -= D[u][0] * a0;                                       \
            if (c2 > 1) s -= D[u][1] * a1;                                       \
            if (c2 > 2) s -= D[u][2] * a2;                                       \
            if (c2 > 3) s -= D[u][3] * a3;                                       \
            if (c2 > 4) s -= D[u][4] * a4;                                       \
            D[u][c2] = s * rinv;                                                 \
        }                                                                        \
    }                                                                            \
} while (0)

// solve + publish to transient panel rows (PROW)*6..: used by B00 and B11
#define PHASE_B(D, PROW) do {                                                    \
    PHASE_B_SOLVE(D);                                                            \
    _Pragma("unroll") for (int u = 0; u < 6; ++u) {                              \
        int prow = (PROW) * 6 + u;                                               \
        *(float4*)&panel[prow * 12]     = make_float4(D[u][0], D[u][1], D[u][2], D[u][3]); \
        *(float2*)&panel[prow * 12 + 4] = make_float2(D[u][4], D[u][5]);         \
    }                                                                            \
} while (0)

// register-sourced scalar persistence of the just-solved acc10 panel rows
#define PERSIST10(D, CB) do {                                                    \
    _Pragma("unroll") for (int u = 0; u < 6; ++u)                                \
        _Pragma("unroll") for (int x = 0; x < 6; ++x)                            \
            Pbuf[(wi * 6 + u) * 49 + (CB) + x] = D[u][x];                        \
} while (0)

// m-outer rank-6, both operands from transient panel (C00, second-half C11)
#define PHASE_C(D, TIEFF, TJEFF) do {                                            \
    _Pragma("unroll") for (int m = 0; m < 6; ++m) {                              \
        float pum[6], pvm[6];                                                    \
        _Pragma("unroll") for (int u = 0; u < 6; ++u)                            \
            pum[u] = panel[((TIEFF) * 6 + u) * 12 + m];                          \
        _Pragma("unroll") for (int v = 0; v < 6; ++v)                            \
            pvm[v] = panel[((TJEFF) * 6 + v) * 12 + m];                          \
        _Pragma("unroll") for (int u = 0; u < 6; ++u)                            \
            _Pragma("unroll") for (int v = 0; v < 6; ++v)                        \
                D[u][v] = fmaf(-pum[u], pvm[v], D[u][v]);                        \
    }                                                                            \
} while (0)

// m-outer rank-6, pu from Pbuf (rows RU), pv from transient panel (rows RV): C10
#define PHASE_C_MIX(D, RU, RV, CB) do {                                          \
    _Pragma("unroll") for (int m = 0; m < 6; ++m) {                              \
        float pum[6], pvm[6];                                                    \
        _Pragma("unroll") for (int u = 0; u < 6; ++u)                            \
            pum[u] = Pbuf[((RU) * 6 + u) * 49 + (CB) + m];                       \
        _Pragma("unroll") for (int v = 0; v < 6; ++v)                            \
            pvm[v] = panel[((RV) * 6 + v) * 12 + m];                             \
        _Pragma("unroll") for (int u = 0; u < 6; ++u)                            \
            _Pragma("unroll") for (int v = 0; v < 6; ++v)                        \
                D[u][v] = fmaf(-pum[u], pvm[v], D[u][v]);                        \
    }                                                                            \
} while (0)

// m-outer rank-6, both from Pbuf: deferred C11 updates
#define PHASE_C_P(D, RU, RV, CB) do {                                            \
    _Pragma("unroll") for (int m = 0; m < 6; ++m) {                              \
        float pum[6], pvm[6];                                                    \
        _Pragma("unroll") for (int u = 0; u < 6; ++u)                            \
            pum[u] = Pbuf[((RU) * 6 + u) * 49 + (CB) + m];                       \
        _Pragma("unroll") for (int v = 0; v < 6; ++v)                            \
            pvm[v] = Pbuf[((RV) * 6 + v) * 49 + (CB) + m];                       \
        _Pragma("unroll") for (int u = 0; u < 6; ++u)                            \
            _Pragma("unroll") for (int v = 0; v < 6; ++v)                        \
                D[u][v] = fmaf(-pum[u], pvm[v], D[u][v]);                        \
    }                                                                            \
} while (0)

#define STORE_TILE(D, TIEFF, TJEFF) do {                                         \
    _Pragma("unroll") for (int u = 0; u < 6; ++u) {                              \
        const int i2 = (TIEFF) * 6 + u;                                          \
        size_t rowp = gbase + (size_t)i2 * NMAT + (TJEFF) * 6;                   \
        _Pragma("unroll") for (int v = 0; v < 6; v += 2) {                       \
            int j0 = (TJEFF) * 6 + v;                                            \
            float a0 = D[u][v], a1 = D[u][v + 1];                                \
            if ((TIEFF) < (TJEFF)) { a0 = 0.0f; a1 = 0.0f; }                     \
            else if ((TIEFF) == (TJEFF)) {                                       \
                if (j0 > i2)     a0 = 0.0f;                                      \
                if (j0 + 1 > i2) a1 = 0.0f;                                      \
            }                                                                    \
            *(float2*)&outL[rowp + v] = make_float2(a0, a1);                     \
        }                                                                        \
    }                                                                            \
} while (0)

#define LOAD_TILE(D, TIEFF, TJEFF) do {                                          \
    _Pragma("unroll") for (int u = 0; u < 6; ++u) {                              \
        size_t rowp = gbase + (size_t)((TIEFF) * 6 + u) * NMAT + (TJEFF) * 6;    \
        float2 p0 = *(const float2*)&outG[rowp + 0];                             \
        float2 p1 = *(const float2*)&outG[rowp + 2];                             \
        float2 p2 = *(const float2*)&outG[rowp + 4];                             \
        D[u][0] = p0.x; D[u][1] = p0.y; D[u][2] = p1.x;                          \
        D[u][3] = p1.y; D[u][4] = p2.x; D[u][5] = p2.y;                          \
    }                                                                            \
} while (0)

__launch_bounds__(256)
__global__ void chol_kernel(const float* __restrict__ outG,
                            float* __restrict__ outL)
{
    const int w    = threadIdx.x >> 6;   // wave id 0..3 -> matrix
    const int lane = threadIdx.x & 63;
    const int wi   = lane >> 3;          // 0..7 row-tile
    const int wj   = lane & 7;           // 0..7 col-tile
    const int b    = blockIdx.x * 4 + w;
    const size_t gbase = (size_t)b * (NMAT * NMAT);

    __shared__ float spanel_all[4][48][12];  // transient panel (rows 0..47)
    __shared__ float sPbuf_all[4][48][49];   // persistent T10/T11 panels
    __shared__ float sL6_all[4][6][8];
    __shared__ float srinv_all[4][8];
    float* panel = &spanel_all[w][0][0];
    float* Pbuf  = &sPbuf_all[w][0][0];
    float* L6p   = &sL6_all[w][0][0];
    float* rinvp = &srinv_all[w][0];

    float acc00[6][6], acc10[6][6];

    LOAD_TILE(acc00, wi,     wj);
    LOAD_TILE(acc10, 8 + wi, wj);

    // ---- first half: factor T00, solve T10 panels (persist-only to Pbuf) ----
    #pragma unroll 1
    for (int jb = 0; jb < 8; ++jb) {
        const int J = jb;
        if (wi == J && wj == J) PHASE_A(acc00);
        SBAR;
        if (wj == J && wi > J) PHASE_B(acc00, wi);
        if (wj == J)           { PHASE_B_SOLVE(acc10); PERSIST10(acc10, J * 6); }
        SBAR;
        if (wj > J && wi >= wj) PHASE_C(acc00, wi, wj);
        if (wj > J)             PHASE_C_MIX(acc10, wi, wj, J * 6);
        SBAR;
    }

    // ---- acc00/acc10 final: store, freeing registers ----
    STORE_TILE(acc00, wi,     wj);
    STORE_TILE(acc10, 8 + wi, wj);
    #pragma unroll
    for (int u = 0; u < 6; ++u) {
        size_t rowp = gbase + (size_t)(wi * 6 + u) * NMAT + (8 + wj) * 6;
        *(float2*)&outL[rowp + 0] = make_float2(0.0f, 0.0f);
        *(float2*)&outL[rowp + 2] = make_float2(0.0f, 0.0f);
        *(float2*)&outL[rowp + 4] = make_float2(0.0f, 0.0f);
    }
    SBAR;

    // ---- load g11; apply the 8 deferred rank-6 updates (jb asc, m asc) ----
    float acc11[6][6];
    LOAD_TILE(acc11, 8 + wi, 8 + wj);
    #pragma unroll 1
    for (int jb2 = 0; jb2 < 8; ++jb2) {
        if (wi >= wj) PHASE_C_P(acc11, wi, wj, jb2 * 6);
        SBAR;
    }

    // ---- second half: panel rows shifted -48 (address-only change) ----
    #pragma unroll 1
    for (int jb = 8; jb < 16; ++jb) {
        const int J = jb - 8;
        if (wi == J && wj == J) PHASE_A(acc11);
        SBAR;
        if (wj == J && wi > J) PHASE_B(acc11, wi);
        SBAR;
        if (wj > J && wi >= wj) PHASE_C(acc11, wi, wj);
        SBAR;
    }

    STORE_TILE(acc11, 8 + wi, 8 + wj);
}

extern "C" void kernel_launch(void* const* d_in, const int* in_sizes, int n_in,
                              void* d_out, int out_size, void* d_ws, size_t ws_size,
                              hipStream_t stream) {
    const float* kp     = (const float*)d_in[0];
    const float* aug    = (const float*)d_in[1];
    const float* scales = (const float*)d_in[2];
    const float* nug    = (const float*)d_in[3];
    float* out = (float*)d_out;
    unsigned* ws = (unsigned*)d_ws;

    float* outG = out;
    float* outL = out + (size_t)NB * NMAT * NMAT;

    hipMemsetAsync(ws, 0xFF, 4, stream);
    minnz_kernel<<<(NB + 255) / 256, 256, 0, stream>>>(scales, ws);
    gram_kernel<<<NB, 256, 0, stream>>>(kp, aug, scales, nug, ws, out);
    chol_kernel<<<NB / 4, 256, 0, stream>>>(outG, outL);
}